// Round 17
// baseline (602.562 us; speedup 1.0000x reference)
//
#include <hip/hip_runtime.h>
#include <math.h>

#define HMOD 128
#define DIN 256
#define NHEADS 4
#define HD 64
#define DSTATE 16
#define NCH 64
#define CONVD 288
#define DPROJ 548
#define LAT 64
#define LSEQ 4096

typedef __attribute__((ext_vector_type(8))) short bf16x8;
typedef __attribute__((ext_vector_type(4))) float f32x4;
typedef __attribute__((ext_vector_type(8))) unsigned short u16x8;
typedef __attribute__((ext_vector_type(4))) unsigned short u16x4;

__device__ __forceinline__ float sigm(float x){ return 1.0f/(1.0f+__expf(-x)); }
__device__ __forceinline__ float siluf(float x){ return x/(1.0f+__expf(-x)); }
__device__ __forceinline__ float softplusf(float x){ return (x>20.0f)? x : log1pf(expf(x)); }
__device__ __forceinline__ float geluf(float x){ return 0.5f*x*(1.0f+erff(x*0.70710678118654752440f)); }
__device__ __forceinline__ unsigned short f2bf(float x){
  unsigned int u = __float_as_uint(x);
  return (unsigned short)((u + 0x7FFFu + ((u>>16)&1u)) >> 16);
}
__device__ __forceinline__ float bf2f(unsigned short h){
  return __uint_as_float(((unsigned int)h)<<16);
}
__device__ __forceinline__ unsigned int cvtpk(float a, float b){
  unsigned int r;
  asm("v_cvt_pk_bf16_f32 %0, %1, %2" : "=v"(r) : "v"(a), "v"(b));
  return r;
}

// ---------------- weight conversion ----------------
__global__ __launch_bounds__(256) void cvt_kernel(const float* __restrict__ in,
  unsigned short* __restrict__ out, int n)
{
  int i = blockIdx.x*256 + threadIdx.x;
  if (i < n) out[i] = f2bf(in[i]);
}
__global__ __launch_bounds__(256) void cvt_nw_kernel(const float* __restrict__ in,
  const float* __restrict__ nw, unsigned short* __restrict__ out, int n)
{
  int i = blockIdx.x*256 + threadIdx.x;
  if (i < n){
    int k = i & 255;
    int li = i >> 15;
    out[i] = f2bf(in[i]*nw[li*256 + k]);
  }
}
__global__ __launch_bounds__(256) void cvt_cw_kernel(const float* __restrict__ in,
  float* __restrict__ out)
{
  int i = blockIdx.x*256 + threadIdx.x;
  if (i < 4608){
    int li = i/1152, r = i - li*1152;
    int ch = r>>2, k = r&3;
    out[li*1152 + k*CONVD + ch] = in[i];
  }
}

// ---------------- embedding ----------------
__global__ __launch_bounds__(256) void embed_kernel(const float* __restrict__ expr,
    const float* __restrict__ ew, const float* __restrict__ eb,
    unsigned short* __restrict__ actA, unsigned short* __restrict__ actB)
{
  int gid = blockIdx.x*256 + threadIdx.x;
  int m = gid >> 7, hh = gid & 127;
  int bl = m >> 12, g = m & 4095;
  unsigned short v = f2bf(expr[m]*ew[hh] + eb[hh]);
  actA[gid] = v;
  actB[(size_t)(((bl<<12) | (4095-g))<<7) + hh] = v;
}

// ---------------- MFMA GEMM (LDS-staged W, swapped operands, dual-stream) --------
template<int KDIM, int NT, int EPI>
__global__ __launch_bounds__(256) void gemm3(
    const unsigned short* __restrict__ A,
    const unsigned short* __restrict__ A2,
    const unsigned short* __restrict__ Wb,
    const float* __restrict__ bias,
    const float* __restrict__ bias2,
    const float* __restrict__ ssqp,
    unsigned short* __restrict__ ob1,
    unsigned short* __restrict__ ob2,
    float* __restrict__ of1,
    float* __restrict__ of2,
    const float* __restrict__ nzp,
    float* __restrict__ of3,
    int N, int ldc, int mhalf, int wsel, int bsel)
{
  __shared__ unsigned short Ws[64*(KDIM+8)];
  __shared__ __align__(16) unsigned short Cb[(EPI==5) ? 8 : 128*72];
  const int tid = threadIdx.x;
  const int m0 = blockIdx.x<<7;
  if (m0 >= mhalf){ Wb += wsel; bias += bsel; }
  const int wid = tid>>6, lane = tid&63;
  const int la = lane&15, kq = lane>>4;
  const int mw = m0 + wid*32;

  bf16x8 af[KDIM/32][2];
  #pragma unroll
  for (int ki=0; ki<KDIM/32; ki++){
    int k = ki*32 + kq*8;
    #pragma unroll
    for (int mf=0; mf<2; mf++){
      int row = mw + mf*16 + la;
      const unsigned short* src;
      if (EPI==2){
        if (k < 128) src = A + (size_t)row*128 + k;
        else { int bl2=row>>12, t=row&4095; src = A2 + (size_t)(((bl2<<12)|(4095-t)))*128 + (k-128); }
      } else {
        src = A + (size_t)row*KDIM + k;
      }
      af[ki][mf] = *(const bf16x8*)src;
    }
  }
  float scv[2];
  if (EPI==4){
    #pragma unroll
    for (int mf=0; mf<2; mf++){
      int m = mw + mf*16 + la;
      float4 s4 = *(const float4*)&ssqp[m*4];
      scv[mf] = rsqrtf((s4.x+s4.y+s4.z+s4.w)*(1.0f/256.0f) + 1e-5f);
    }
  }
  f32x4 vlm[2][4];

  const int KD8 = KDIM/8;
  for (int nt=0; nt<NT; nt++){
    int n0 = (blockIdx.y*NT + nt)<<6;
    for (int ci = tid; ci < 64*KD8; ci += 256){
      int row = ci/KD8, kc = (ci - row*KD8)*8;
      int n = n0 + row;
      bf16x8 v = {0,0,0,0,0,0,0,0};
      if (n < N) v = *(const bf16x8*)&Wb[(size_t)n*KDIM + kc];
      *(bf16x8*)&Ws[row*(KDIM+8) + kc] = v;
    }
    __syncthreads();
    f32x4 acc[2][4] = {};
    #pragma unroll
    for (int ki=0; ki<KDIM/32; ki++){
      #pragma unroll
      for (int nf=0; nf<4; nf++){
        bf16x8 wfr = *(const bf16x8*)&Ws[(nf*16 + la)*(KDIM+8) + ki*32 + kq*8];
        #pragma unroll
        for (int mf=0; mf<2; mf++)
          acc[mf][nf] = __builtin_amdgcn_mfma_f32_16x16x32_bf16(wfr, af[ki][mf], acc[mf][nf], 0,0,0);
      }
    }
    #pragma unroll
    for (int mf=0; mf<2; mf++){
      #pragma unroll
      for (int nf=0; nf<4; nf++){
        int m    = mw + mf*16 + la;
        int row  = wid*32 + mf*16 + la;
        int colb = nf*16 + kq*4;
        int nb   = n0 + colb;
        f32x4 v = acc[mf][nf];
        if (EPI==1){
          if (nb >= DIN+CONVD){
            if (nb < DPROJ){
              float4 o;
              o.x = softplusf(v[0] + bias[0]); o.y = softplusf(v[1] + bias[1]);
              o.z = softplusf(v[2] + bias[2]); o.w = softplusf(v[3] + bias[3]);
              *(float4*)&of1[(size_t)m*NHEADS] = o;
            }
          } else {
            unsigned int pr[2];
            pr[0] = cvtpk(v[0], v[1]); pr[1] = cvtpk(v[2], v[3]);
            *(u16x4*)&Cb[row*72 + colb] = *(const u16x4*)pr;
          }
        } else if (EPI==2){
          float4 b4 = *(const float4*)&bias[nb];
          unsigned int pr[2];
          pr[0] = cvtpk(geluf(v[0]+b4.x), geluf(v[1]+b4.y));
          pr[1] = cvtpk(geluf(v[2]+b4.z), geluf(v[3]+b4.w));
          *(u16x4*)&Cb[row*72 + colb] = *(const u16x4*)pr;
        } else if (EPI==4){
          unsigned int pr[2];
          pr[0] = cvtpk(v[0]*scv[mf], v[1]*scv[mf]);
          pr[1] = cvtpk(v[2]*scv[mf], v[3]*scv[mf]);
          *(u16x4*)&Cb[row*72 + colb] = *(const u16x4*)pr;
        } else if (EPI==5){
          if (nt == 0){
            float4 b4 = *(const float4*)&bias[colb];
            f32x4 lm; lm[0]=v[0]+b4.x; lm[1]=v[1]+b4.y; lm[2]=v[2]+b4.z; lm[3]=v[3]+b4.w;
            vlm[mf][nf] = lm;
            *(f32x4*)&of1[(size_t)m*64 + colb] = lm;
          } else {
            float4 b4 = *(const float4*)&bias2[colb];
            f32x4 lv; lv[0]=v[0]+b4.x; lv[1]=v[1]+b4.y; lv[2]=v[2]+b4.z; lv[3]=v[3]+b4.w;
            *(f32x4*)&of2[(size_t)m*64 + colb] = lv;
            f32x4 nz = *(const f32x4*)&nzp[(size_t)m*64 + colb];
            f32x4 sp;
            #pragma unroll
            for (int j=0;j<4;j++) sp[j] = fmaf(nz[j], expf(0.5f*lv[j]), vlm[mf][nf][j]);
            *(f32x4*)&of3[(size_t)m*64 + colb] = sp;
          }
        }
      }
    }
    if (EPI!=5){
      __syncthreads();
      #pragma unroll
      for (int j=0; j<4; j++){
        int row = (tid>>3) + j*32;
        int col0 = (tid&7)*8;
        int m = m0 + row;
        int nch = n0 + col0;
        u16x8 val = *(const u16x8*)&Cb[row*72 + col0];
        if (EPI==1){
          if (nch < DIN)            *(u16x8*)&ob1[(size_t)m*DIN + nch] = val;
          else if (nch < DIN+CONVD) *(u16x8*)&ob2[(size_t)m*CONVD + (nch-DIN)] = val;
        } else {
          *(u16x8*)&ob1[(size_t)m*ldc + nch] = val;
        }
      }
    }
    __syncthreads();
  }
}

// ---------------- fused conv helper ------------------------------------------------
__device__ __forceinline__ void conv8(const unsigned short* __restrict__ xraw,
  const float* __restrict__ cwT, const float* __restrict__ cb,
  int seqbase, int t, int ch0, bool full, u16x8* out)
{
  float acc[8];
  float4 b0 = *(const float4*)&cb[ch0];
  float4 b1 = *(const float4*)&cb[ch0+4];
  acc[0]=b0.x; acc[1]=b0.y; acc[2]=b0.z; acc[3]=b0.w;
  acc[4]=b1.x; acc[5]=b1.y; acc[6]=b1.z; acc[7]=b1.w;
  if (full){
    #pragma unroll
    for (int k=0;k<4;k++){
      u16x8 xv = *(const u16x8*)&xraw[(size_t)(seqbase+t-3+k)*CONVD + ch0];
      float4 w0 = *(const float4*)&cwT[k*CONVD + ch0];
      float4 w1 = *(const float4*)&cwT[k*CONVD + ch0 + 4];
      float w[8] = {w0.x,w0.y,w0.z,w0.w,w1.x,w1.y,w1.z,w1.w};
      #pragma unroll
      for (int j=0;j<8;j++) acc[j] = fmaf(w[j], bf2f(xv[j]), acc[j]);
    }
  } else {
    #pragma unroll
    for (int k=0;k<4;k++){
      int tt = t - 3 + k;
      if (tt >= 0){
        u16x8 xv = *(const u16x8*)&xraw[(size_t)(seqbase+tt)*CONVD + ch0];
        float4 w0 = *(const float4*)&cwT[k*CONVD + ch0];
        float4 w1 = *(const float4*)&cwT[k*CONVD + ch0 + 4];
        float w[8] = {w0.x,w0.y,w0.z,w0.w,w1.x,w1.y,w1.z,w1.w};
        #pragma unroll
        for (int j=0;j<8;j++) acc[j] = fmaf(w[j], bf2f(xv[j]), acc[j]);
      }
    }
  }
  unsigned int pr[4];
  pr[0] = cvtpk(siluf(acc[0]), siluf(acc[1]));
  pr[1] = cvtpk(siluf(acc[2]), siluf(acc[3]));
  pr[2] = cvtpk(siluf(acc[4]), siluf(acc[5]));
  pr[3] = cvtpk(siluf(acc[6]), siluf(acc[7]));
  *out = *(const u16x8*)pr;
}

// ---------------- SSD front: fused conv (direct-transposed Xt), cumsum, states -----
__global__ __launch_bounds__(256) void ssd_front(
  const unsigned short* __restrict__ xraw, const float* __restrict__ dtsp,
  const float* __restrict__ Alog,
  const float* __restrict__ cwT, const float* __restrict__ cb,
  unsigned short* __restrict__ states_g, float* __restrict__ acs_g,
  float* __restrict__ atot_g, int BGs)
{
  __shared__ __align__(16) unsigned short Xt[64*72];    // [ch][l]
  __shared__ __align__(16) unsigned short Braw[64*24];  // [l][n]
  __shared__ __align__(16) unsigned short Bwt[16*88];   // [n][l]
  __shared__ float acs_s[64], dts_s[64];
  const int bx = blockIdx.x;
  const int h = bx & 3, c = (bx>>2)&63, bl = bx>>8;
  const int tid = threadIdx.x;
  const int tokbase = (bl<<12) + (c<<6);
  const int seqbase = bl<<12;
  const int s1 = (bl >= BGs);
  const float* cwTs = cwT + (s1 ? 2304 : 0);
  const float* cbs  = cb  + (s1 ? 576  : 0);
  const bool full = (c > 0);

  if (tid < 64) {
    float dt = dtsp[(size_t)(tokbase+tid)*NHEADS + h];
    dts_s[tid] = dt;
    float xsc = -__expf(Alog[(s1?8:0) + h]) * dt;
    #pragma unroll
    for (int off=1; off<64; off<<=1){ float v = __shfl_up(xsc, off); if (tid >= off) xsc += v; }
    acs_s[tid] = xsc;
    acs_g[(size_t)bx*64 + tid] = xsc;
  }
  // fused conv: wave gs handles groups {gs, gs+4, gs+8<10}
  {
    const int l = tid & 63, gs = tid >> 6;
    const int t = (c<<6) + l;
    #pragma unroll
    for (int i=0;i<3;i++){
      int g = gs + i*4;
      if (g < 10){
        int ch0 = (g<8) ? (h<<6)+g*8 : 256+(g-8)*8;
        u16x8 o;
        conv8(xraw, cwTs, cbs, seqbase, t, ch0, full, &o);
        if (g<8){
          #pragma unroll
          for (int j=0;j<8;j++) Xt[(g*8+j)*72 + l] = o[j];
        } else {
          *(u16x8*)&Braw[l*24 + (g-8)*8] = o;
        }
      }
    }
  }
  __syncthreads();
  const float atotv = acs_s[63];
  if (tid==0) atot_g[bx] = atotv;
  if (tid < 128){
    int ch = tid & 15, l0 = (tid>>4)*8;
    float vals[8];
    #pragma unroll
    for (int j=0;j<8;j++){
      int l = l0+j;
      vals[j] = bf2f(Braw[l*24 + ch]) * __expf(atotv - acs_s[l]) * dts_s[l];
    }
    unsigned int pr[4];
    pr[0]=cvtpk(vals[0],vals[1]); pr[1]=cvtpk(vals[2],vals[3]);
    pr[2]=cvtpk(vals[4],vals[5]); pr[3]=cvtpk(vals[6],vals[7]);
    *(u16x8*)&Bwt[ch*88 + l0] = *(const u16x8*)pr;
  }
  __syncthreads();
  const int wid = tid>>6, lane = tid&63;
  const int la = lane&15, kq = lane>>4;
  f32x4 acc = {0.f,0.f,0.f,0.f};
  #pragma unroll
  for (int kt=0; kt<2; kt++){
    bf16x8 a = *(const bf16x8*)&Xt[(wid*16+la)*72 + kt*32+kq*8];
    bf16x8 b = *(const bf16x8*)&Bwt[la*88 + kt*32+kq*8];
    acc = __builtin_amdgcn_mfma_f32_16x16x32_bf16(a, b, acc, 0,0,0);
  }
  size_t base = (size_t)bx<<10;
  {
    unsigned int s01 = cvtpk(acc[0], acc[1]);
    unsigned int s23 = cvtpk(acc[2], acc[3]);
    int p0 = wid*16 + kq*4;
    states_g[base + (size_t)(p0+0)*16 + la] = (unsigned short)s01;
    states_g[base + (size_t)(p0+1)*16 + la] = (unsigned short)(s01>>16);
    states_g[base + (size_t)(p0+2)*16 + la] = (unsigned short)s23;
    states_g[base + (size_t)(p0+3)*16 + la] = (unsigned short)(s23>>16);
  }
}

// ---------------- inter-chunk state scan (bf16 storage, fp32 carry) ----------------
__global__ __launch_bounds__(256) void scan_kernel(unsigned short* __restrict__ states,
  const float* __restrict__ atot)
{
  int gid = blockIdx.x*256 + threadIdx.x;
  int inner = gid & 1023;
  int h = (gid>>10)&3;
  int bl = gid>>12;
  size_t base = (size_t)bl*262144 + h*1024 + inner;
  int abase = bl*256 + h;
  float v[64];
  #pragma unroll
  for (int c2=0;c2<64;c2++) v[c2] = bf2f(states[base + (size_t)c2*4096]);
  float S = 0.0f;
  #pragma unroll
  for (int c2=0;c2<64;c2++){
    states[base + (size_t)c2*4096] = f2bf(S);
    S = __expf(atot[abase + c2*4])*S + v[c2];
  }
}

// ---------------- SSD back: conv->Xt direct, states from global, 25KB LDS ----------
__global__ __launch_bounds__(256) void ssd_back(
  const unsigned short* __restrict__ xraw, unsigned short* __restrict__ zyf,
  const float* __restrict__ dtsp, const float* __restrict__ acs_g,
  const unsigned short* __restrict__ states, const float* __restrict__ Dp,
  const float* __restrict__ cwT, const float* __restrict__ cb,
  float* __restrict__ ssqp, int BGs)
{
  __shared__ __align__(16) unsigned short U[2*64*72];    // Xt | Sb ; later Yl f32
  __shared__ __align__(16) unsigned short CBS[2*64*24];  // Cp | Bp (stride 24)
  __shared__ float acs_s[64], dts_s[64];
  unsigned short* Xt = U;                  // [ch][l] stride 72
  unsigned short* Sb = U + 64*72;          // Sb[l][s] stride 72
  unsigned short* Bp = CBS;
  unsigned short* Cp = CBS + 64*24;
  float* Yl = (float*)U;                   // [l][p] stride 68
  const int bx = blockIdx.x;
  const int h = bx & 3, c = (bx>>2)&63, bl = bx>>8;
  const int tid = threadIdx.x;
  const int tokbase = (bl<<12) + (c<<6);
  const int seqbase = bl<<12;
  const int s1 = (bl >= BGs);
  const float* cwTs = cwT + (s1 ? 2304 : 0);
  const float* cbs  = cb  + (s1 ? 576  : 0);
  const float Dh = Dp[(s1?8:0) + h];
  const bool full = (c > 0);

  if (tid < 64) {
    dts_s[tid] = dtsp[(size_t)(tokbase+tid)*NHEADS + h];
    acs_s[tid] = acs_g[(size_t)bx*64 + tid];
  }
  // fused conv: wave gs handles groups {gs, gs+4, gs+8}; x -> Xt transposed scalar
  {
    const int l = tid & 63, gs = tid >> 6;
    const int t = (c<<6) + l;
    #pragma unroll
    for (int i=0;i<3;i++){
      int g = gs + i*4;
      int ch0 = (g<8) ? (h<<6)+g*8 : 256+(g-8)*8;
      u16x8 o;
      conv8(xraw, cwTs, cbs, seqbase, t, ch0, full, &o);
      if (g<8){
        #pragma unroll
        for (int j=0;j<8;j++) Xt[(g*8+j)*72 + l] = o[j];
      } else if (g<10){
        *(u16x8*)&Bp[l*24 + (g-8)*8] = o;
      } else {
        *(u16x8*)&Cp[l*24 + (g-10)*8] = o;
      }
    }
  }
  __syncthreads();

  const int wid = tid>>6, lane = tid&63;
  const int la = lane&15, kq = lane>>4;
  const int L0 = wid*16;
  const f32x4 zero4 = {0.f,0.f,0.f,0.f};
  const bf16x8 zfrag = {0,0,0,0,0,0,0,0};

  // CB = C·B^T (K=32, upper-half fragments zero) -> mask/scale, fold D -> Sb bf16
  {
    bf16x8 a = (kq<2) ? *(const bf16x8*)&Cp[(L0+la)*24 + kq*8] : zfrag;
    f32x4 cbacc[4];
    #pragma unroll
    for (int nf=0; nf<4; nf++){
      bf16x8 b = (kq<2) ? *(const bf16x8*)&Bp[(nf*16+la)*24 + kq*8] : zfrag;
      cbacc[nf] = __builtin_amdgcn_mfma_f32_16x16x32_bf16(a, b, zero4, 0,0,0);
    }
    #pragma unroll
    for (int nf=0; nf<4; nf++){
      int s = nf*16 + la;
      float vv[4];
      #pragma unroll
      for (int r=0; r<4; r++){
        int l = L0 + kq*4 + r;
        float v = 0.f;
        if (s <= l) v = __expf(acs_s[l]-acs_s[s])*dts_s[s]*cbacc[nf][r];
        if (s == l) v += Dh;
        vv[r] = v;
      }
      unsigned int p01 = cvtpk(vv[0], vv[1]);
      unsigned int p23 = cvtpk(vv[2], vv[3]);
      int lb = L0 + kq*4;
      Sb[(lb+0)*72 + s] = (unsigned short)p01;
      Sb[(lb+1)*72 + s] = (unsigned short)(p01>>16);
      Sb[(lb+2)*72 + s] = (unsigned short)p23;
      Sb[(lb+3)*72 + s] = (unsigned short)(p23>>16);
    }
  }
  // Y_off = C·states^T (states fragments straight from global), scale exp(acs[l])
  f32x4 ya[4];
  {
    bf16x8 a = (kq<2) ? *(const bf16x8*)&Cp[(L0+la)*24 + kq*8] : zfrag;
    #pragma unroll
    for (int nf=0; nf<4; nf++){
      bf16x8 b = (kq<2) ? *(const bf16x8*)&states[((size_t)bx<<10) + (size_t)(nf*16+la)*16 + kq*8] : zfrag;
      ya[nf] = __builtin_amdgcn_mfma_f32_16x16x32_bf16(a, b, zero4, 0,0,0);
    }
    float eal[4];
    #pragma unroll
    for (int r=0; r<4; r++) eal[r] = __expf(acs_s[L0 + kq*4 + r]);
    #pragma unroll
    for (int nf=0; nf<4; nf++)
      #pragma unroll
      for (int r=0; r<4; r++) ya[nf][r] *= eal[r];
  }
  // Y_diag += Sb·Xt^T (K=64); A-operand reads only own-wave Sb rows
  #pragma unroll
  for (int kt=0; kt<2; kt++){
    bf16x8 a = *(const bf16x8*)&Sb[(L0+la)*72 + kt*32+kq*8];
    #pragma unroll
    for (int nf=0; nf<4; nf++){
      bf16x8 b = *(const bf16x8*)&Xt[(nf*16+la)*72 + kt*32+kq*8];
      ya[nf] = __builtin_amdgcn_mfma_f32_16x16x32_bf16(a, b, ya[nf], 0,0,0);
    }
  }
  __syncthreads();   // all waves done reading Xt/Sb -> Yl alias safe
  #pragma unroll
  for (int nf=0; nf<4; nf++){
    #pragma unroll
    for (int r=0; r<4; r++){
      int l = L0 + kq*4 + r, p = nf*16 + la;
      Yl[l*68 + p] = ya[nf][r];
    }
  }
  __syncthreads();
  #pragma unroll
  for (int i=0;i<2;i++){
    int u = tid + (i<<8);
    int l = u>>3, g = u&7;
    size_t gidx = (size_t)(tokbase+l)*DIN + (h<<6) + g*8;
    u16x8 z8 = *(const u16x8*)&zyf[gidx];
    float yv[8];
    float ps = 0.f;
    #pragma unroll
    for (int j=0;j<8;j++){
      float y = Yl[l*68 + g*8 + j];
      float zv = bf2f(z8[j]);
      yv[j] = y * zv * sigm(zv);
      ps = fmaf(yv[j], yv[j], ps);
    }
    unsigned int pr[4];
    pr[0]=cvtpk(yv[0],yv[1]); pr[1]=cvtpk(yv[2],yv[3]);
    pr[2]=cvtpk(yv[4],yv[5]); pr[3]=cvtpk(yv[6],yv[7]);
    *(u16x8*)&zyf[gidx] = *(const u16x8*)pr;
    ps += __shfl_xor(ps, 1); ps += __shfl_xor(ps, 2); ps += __shfl_xor(ps, 4);
    if (g == 0) ssqp[(size_t)(tokbase+l)*NHEADS + h] = ps;
  }
}

// ---------------- predgate -------------------------------------------------------
__global__ __launch_bounds__(256) void predgate_kernel(
  const unsigned short* __restrict__ fused, const float* __restrict__ sample,
  const unsigned short* __restrict__ gwb, const float* __restrict__ gb,
  const float* __restrict__ ow, const float* __restrict__ ob,
  const float* __restrict__ rg, float* __restrict__ pred)
{
  __shared__ __align__(16) unsigned short Ws[64*72];
  __shared__ __align__(16) float Gp[128*68];
  const int tid = threadIdx.x;
  const int m0 = blockIdx.x<<7;
  const int wid = tid>>6, lane = tid&63;
  const int la = lane&15, kq = lane>>4;
  const int mw = m0 + wid*32;

  bf16x8 af[2][2];
  #pragma unroll
  for (int ki=0; ki<2; ki++){
    int k = ki*32 + kq*8;
    #pragma unroll
    for (int mf=0; mf<2; mf++){
      int row = mw + mf*16 + la;
      float4 s0 = *(const float4*)&sample[(size_t)row*64 + k];
      float4 s1 = *(const float4*)&sample[(size_t)row*64 + k + 4];
      unsigned int pr[4];
      pr[0]=cvtpk(s0.x,s0.y); pr[1]=cvtpk(s0.z,s0.w);
      pr[2]=cvtpk(s1.x,s1.y); pr[3]=cvtpk(s1.z,s1.w);
      af[ki][mf] = *(const bf16x8*)pr;
    }
  }
  const float ob0 = ob[0];
  const int prow = tid>>1, phalf = tid&1;
  float rs = 0.f;

  #pragma unroll
  for (int nt=0; nt<2; nt++){
    int n0 = nt<<6;
    #pragma unroll
    for (int i=0;i<2;i++){
      int slot = tid + (i<<8);
      int row = slot>>3, g = slot&7;
      *(u16x8*)&Ws[row*72 + g*8] = *(const u16x8*)&gwb[(size_t)(n0+row)*64 + g*8];
    }
    __syncthreads();
    f32x4 acc[2][4] = {};
    #pragma unroll
    for (int ki=0; ki<2; ki++){
      #pragma unroll
      for (int nf=0; nf<4; nf++){
        bf16x8 bfr = *(const bf16x8*)&Ws[(nf*16 + la)*72 + ki*32 + kq*8];
        #pragma unroll
        for (int mf=0; mf<2; mf++)
          acc[mf][nf] = __builtin_amdgcn_mfma_f32_16x16x32_bf16(af[ki][mf], bfr, acc[mf][nf], 0,0,0);
      }
    }
    #pragma unroll
    for (int mf=0; mf<2; mf++){
      #pragma unroll
      for (int nf=0; nf<4; nf++){
        #pragma unroll
        for (int r=0; r<4; r++){
          int row = wid*32 + mf*16 + kq*4 + r;
          int col = nf*16 + la;
          int n = n0 + col;
          Gp[row*68 + col] = sigm(acc[mf][nf][r] + gb[n]) * ow[n];
        }
      }
    }
    __syncthreads();
    #pragma unroll
    for (int q=0; q<4; q++){
      int col0 = phalf*32 + q*8;
      u16x8 f8 = *(const u16x8*)&fused[(size_t)(m0+prow)*128 + n0 + col0];
      float4 g0 = *(const float4*)&Gp[prow*68 + col0];
      float4 g1 = *(const float4*)&Gp[prow*68 + col0 + 4];
      rs = fmaf(bf2f(f8[0]), g0.x, rs); rs = fmaf(bf2f(f8[1]), g0.y, rs);
      rs = fmaf(bf2f(f8[2]), g0.z, rs); rs = fmaf(bf2f(f8[3]), g0.w, rs);
      rs = fmaf(bf2f(f8[4]), g1.x, rs); rs = fmaf(bf2f(f8[5]), g1.y, rs);
      rs = fmaf(bf2f(f8[6]), g1.z, rs); rs = fmaf(bf2f(f8[7]), g1.w, rs);
    }
    __syncthreads();
  }
  rs += __shfl_xor(rs, 1);
  if (phalf == 0){
    int m = m0 + prow;
    pred[m] = (rs + ob0) * sigm(rg[m & 4095]);
  }
}

extern "C" void kernel_launch(void* const* d_in, const int* in_sizes, int n_in,
                              void* d_out, int out_size, void* d_ws, size_t ws_size,
                              hipStream_t stream)
{
  const float* expr      = (const float*)d_in[0];
  const float* noise     = (const float*)d_in[1];
  const float* expr_w    = (const float*)d_in[2];
  const float* expr_b    = (const float*)d_in[3];
  const float* in_proj_w = (const float*)d_in[4];
  const float* conv_w    = (const float*)d_in[5];
  const float* conv_b    = (const float*)d_in[6];
  const float* dt_bias   = (const float*)d_in[7];
  const float* A_log     = (const float*)d_in[8];
  const float* D_par     = (const float*)d_in[9];
  const float* norm_w    = (const float*)d_in[10];
  const float* out_proj_w= (const float*)d_in[11];
  const float* fusion_w  = (const float*)d_in[12];
  const float* fusion_b  = (const float*)d_in[13];
  const float* lm_w      = (const float*)d_in[14];
  const float* lm_b      = (const float*)d_in[15];
  const float* lv_w      = (const float*)d_in[16];
  const float* lv_b      = (const float*)d_in[17];
  const float* gate_w    = (const float*)d_in[18];
  const float* gate_b    = (const float*)d_in[19];
  const float* outp_w    = (const float*)d_in[20];
  const float* outp_b    = (const float*)d_in[21];
  const float* reg_gate  = (const float*)d_in[22];

  const size_t WBYTES = 956416;
  const int IMAX = 0x7fffffff;
  int BG = 0;
  const int cands[5] = {16, 8, 4, 2, 1};
  for (int ci = 0; ci < 5; ci++) {
    int c2 = cands[ci];
    size_t MG2c = (size_t)2 * c2 * LSEQ;
    size_t need = WBYTES + MG2c*1520 + (size_t)c2*2048 + 256;
    if (need <= ws_size) { BG = c2; break; }
  }
  if (!BG) return;
  const size_t MG  = (size_t)BG * LSEQ;
  const size_t MG2 = 2*MG;

  unsigned short* wip = (unsigned short*)d_ws;
  unsigned short* wop = wip + 280576;
  unsigned short* wfu = wop + 131072;
  unsigned short* wlm = wfu + 32768;
  unsigned short* wlv = wlm + 8192;
  unsigned short* wgw = wlv + 8192;
  float* cwT   = (float*)(wgw + 8192);
  float* dtsp  = (float*)((char*)d_ws + WBYTES);
  float* acs   = dtsp + MG2*4;
  float* atot  = acs  + MG2*4;
  float* ssqp  = atot + (size_t)2*BG*256;
  unsigned short* statesb = (unsigned short*)(ssqp + MG2*4);
  unsigned short* zyf   = statesb + MG2*64;
  unsigned short* xrawb = zyf + MG2*256;
  unsigned short* act   = xrawb + MG2*288;
  unsigned short* actA  = act;
  unsigned short* actB  = act + MG*128;
  unsigned short* fusedbf = zyf;

  float* out_pred_g = (float*)d_out;
  float* out_lm_g   = out_pred_g + (size_t)16*LSEQ;
  float* out_lv_g   = out_lm_g   + (size_t)16*LSEQ*LAT;
  float* out_samp_g = out_lv_g   + (size_t)16*LSEQ*LAT;

  cvt_kernel<<<(280576+255)/256, 256, 0, stream>>>(in_proj_w, wip, 280576);
  cvt_nw_kernel<<<131072/256,    256, 0, stream>>>(out_proj_w, norm_w, wop, 131072);
  cvt_kernel<<<32768/256,        256, 0, stream>>>(fusion_w, wfu, 32768);
  cvt_kernel<<<8192/256,         256, 0, stream>>>(lm_w, wlm, 8192);
  cvt_kernel<<<8192/256,         256, 0, stream>>>(lv_w, wlv, 8192);
  cvt_kernel<<<8192/256,         256, 0, stream>>>(gate_w, wgw, 8192);
  cvt_cw_kernel<<<(4608+255)/256, 256, 0, stream>>>(conv_w, cwT);

  for (int b0 = 0; b0 < 16; b0 += BG) {
    float* out_pred = out_pred_g + (size_t)b0*LSEQ;
    float* out_lm   = out_lm_g   + (size_t)b0*LSEQ*LAT;
    float* out_lv   = out_lv_g   + (size_t)b0*LSEQ*LAT;
    float* out_samp = out_samp_g + (size_t)b0*LSEQ*LAT;
    const float* nz = noise      + (size_t)b0*LSEQ*LAT;

    embed_kernel<<<(MG*128)/256, 256, 0, stream>>>(expr + (size_t)b0*LSEQ, expr_w, expr_b, actA, actB);

    for (int p = 0; p < 2; p++) {
      const unsigned short* Wi = wip + (size_t)p*DPROJ*HMOD;
      const unsigned short* Wo = wop + (size_t)p*HMOD*DIN;
      const float* cwTl = cwT + (size_t)p*1152;
      const float* cb   = conv_b + (size_t)p*CONVD;
      const float* dtb  = dt_bias + (size_t)p*NHEADS;
      const float* Al   = A_log + (size_t)p*NHEADS;
      const float* Dl   = D_par + (size_t)p*NHEADS;

      gemm3<128,3,1><<<dim3(MG2/128, 3), 256, 0, stream>>>(act, nullptr, Wi, dtb, nullptr, nullptr,
        zyf, xrawb, dtsp, nullptr, nullptr, nullptr, DPROJ, 0, (int)MG, 2*DPROJ*HMOD, 2*NHEADS);
      ssd_front<<<2*BG*256, 256, 0, stream>>>(xrawb, dtsp, Al, cwTl, cb, statesb, acs, atot, BG);
      scan_kernel<<<(2*BG*LSEQ)/256, 256, 0, stream>>>(statesb, atot);
      ssd_back<<<2*BG*256, 256, 0, stream>>>(xrawb, zyf, dtsp, acs, statesb, Dl, cwTl, cb, ssqp, BG);
      gemm3<256,1,4><<<dim3(MG2/128, 2), 256, 0, stream>>>(zyf, nullptr, Wo, nullptr, nullptr, ssqp,
        act, nullptr, nullptr, nullptr, nullptr, nullptr, HMOD, HMOD, (int)MG, 2*HMOD*DIN, 0);
    }

    gemm3<256,1,2><<<dim3(MG/128, 2), 256, 0, stream>>>(actA, actB, wfu, fusion_b, nullptr, nullptr,
      fusedbf, nullptr, nullptr, nullptr, nullptr, nullptr, HMOD, HMOD, IMAX, 0, 0);
    gemm3<128,2,5><<<dim3(MG/128, 1), 256, 0, stream>>>(fusedbf, nullptr, wlm, lm_b, lv_b, nullptr,
      nullptr, nullptr, out_lm, out_lv, nz, out_samp, 128, LAT, IMAX, 0, 0);
    predgate_kernel<<<MG/128, 256, 0, stream>>>(fusedbf, out_samp, wgw, gate_b, outp_w, outp_b, reg_gate, out_pred);
  }
}

// Round 18
// 582.027 us; speedup vs baseline: 1.0353x; 1.0353x over previous
//
#include <hip/hip_runtime.h>
#include <math.h>

#define HMOD 128
#define DIN 256
#define NHEADS 4
#define HD 64
#define DSTATE 16
#define NCH 64
#define CONVD 288
#define DPROJ 548
#define LAT 64
#define LSEQ 4096

typedef __attribute__((ext_vector_type(8))) short bf16x8;
typedef __attribute__((ext_vector_type(4))) float f32x4;
typedef __attribute__((ext_vector_type(8))) unsigned short u16x8;
typedef __attribute__((ext_vector_type(4))) unsigned short u16x4;

__device__ __forceinline__ float sigm(float x){ return 1.0f/(1.0f+__expf(-x)); }
__device__ __forceinline__ float siluf(float x){ return x/(1.0f+__expf(-x)); }
__device__ __forceinline__ float softplusf(float x){ return (x>20.0f)? x : log1pf(expf(x)); }
__device__ __forceinline__ float geluf(float x){ return 0.5f*x*(1.0f+erff(x*0.70710678118654752440f)); }
__device__ __forceinline__ unsigned short f2bf(float x){
  unsigned int u = __float_as_uint(x);
  return (unsigned short)((u + 0x7FFFu + ((u>>16)&1u)) >> 16);
}
__device__ __forceinline__ float bf2f(unsigned short h){
  return __uint_as_float(((unsigned int)h)<<16);
}
__device__ __forceinline__ unsigned int cvtpk(float a, float b){
  unsigned int r;
  asm("v_cvt_pk_bf16_f32 %0, %1, %2" : "=v"(r) : "v"(a), "v"(b));
  return r;
}

// ---------------- weight conversion ----------------
__global__ __launch_bounds__(256) void cvt_kernel(const float* __restrict__ in,
  unsigned short* __restrict__ out, int n)
{
  int i = blockIdx.x*256 + threadIdx.x;
  if (i < n) out[i] = f2bf(in[i]);
}
__global__ __launch_bounds__(256) void cvt_nw_kernel(const float* __restrict__ in,
  const float* __restrict__ nw, unsigned short* __restrict__ out, int n)
{
  int i = blockIdx.x*256 + threadIdx.x;
  if (i < n){
    int k = i & 255;
    int li = i >> 15;
    out[i] = f2bf(in[i]*nw[li*256 + k]);
  }
}
__global__ __launch_bounds__(256) void cvt_cw_kernel(const float* __restrict__ in,
  float* __restrict__ out)
{
  int i = blockIdx.x*256 + threadIdx.x;
  if (i < 4608){
    int li = i/1152, r = i - li*1152;
    int ch = r>>2, k = r&3;
    out[li*1152 + k*CONVD + ch] = in[i];
  }
}

// ---------------- embedding ----------------
__global__ __launch_bounds__(256) void embed_kernel(const float* __restrict__ expr,
    const float* __restrict__ ew, const float* __restrict__ eb,
    unsigned short* __restrict__ actA, unsigned short* __restrict__ actB)
{
  int gid = blockIdx.x*256 + threadIdx.x;
  int m = gid >> 7, hh = gid & 127;
  int bl = m >> 12, g = m & 4095;
  unsigned short v = f2bf(expr[m]*ew[hh] + eb[hh]);
  actA[gid] = v;
  actB[(size_t)(((bl<<12) | (4095-g))<<7) + hh] = v;
}

// ---------------- MFMA GEMM (LDS-staged W, swapped operands, dual-stream) --------
template<int KDIM, int NT, int EPI>
__global__ __launch_bounds__(256) void gemm3(
    const unsigned short* __restrict__ A,
    const unsigned short* __restrict__ A2,
    const unsigned short* __restrict__ Wb,
    const float* __restrict__ bias,
    const float* __restrict__ bias2,
    const float* __restrict__ ssqp,
    unsigned short* __restrict__ ob1,
    unsigned short* __restrict__ ob2,
    float* __restrict__ of1,
    float* __restrict__ of2,
    const float* __restrict__ nzp,
    float* __restrict__ of3,
    int N, int ldc, int mhalf, int wsel, int bsel)
{
  __shared__ unsigned short Ws[64*(KDIM+8)];
  __shared__ __align__(16) unsigned short Cb[(EPI==5) ? 8 : 128*72];
  const int tid = threadIdx.x;
  const int m0 = blockIdx.x<<7;
  if (m0 >= mhalf){ Wb += wsel; bias += bsel; }
  const int wid = tid>>6, lane = tid&63;
  const int la = lane&15, kq = lane>>4;
  const int mw = m0 + wid*32;

  bf16x8 af[KDIM/32][2];
  #pragma unroll
  for (int ki=0; ki<KDIM/32; ki++){
    int k = ki*32 + kq*8;
    #pragma unroll
    for (int mf=0; mf<2; mf++){
      int row = mw + mf*16 + la;
      const unsigned short* src;
      if (EPI==2){
        if (k < 128) src = A + (size_t)row*128 + k;
        else { int bl2=row>>12, t=row&4095; src = A2 + (size_t)(((bl2<<12)|(4095-t)))*128 + (k-128); }
      } else {
        src = A + (size_t)row*KDIM + k;
      }
      af[ki][mf] = *(const bf16x8*)src;
    }
  }
  float scv[2];
  if (EPI==4){
    #pragma unroll
    for (int mf=0; mf<2; mf++){
      int m = mw + mf*16 + la;
      float4 s4 = *(const float4*)&ssqp[m*4];
      scv[mf] = rsqrtf((s4.x+s4.y+s4.z+s4.w)*(1.0f/256.0f) + 1e-5f);
    }
  }
  f32x4 vlm[2][4];

  const int KD8 = KDIM/8;
  for (int nt=0; nt<NT; nt++){
    int n0 = (blockIdx.y*NT + nt)<<6;
    for (int ci = tid; ci < 64*KD8; ci += 256){
      int row = ci/KD8, kc = (ci - row*KD8)*8;
      int n = n0 + row;
      bf16x8 v = {0,0,0,0,0,0,0,0};
      if (n < N) v = *(const bf16x8*)&Wb[(size_t)n*KDIM + kc];
      *(bf16x8*)&Ws[row*(KDIM+8) + kc] = v;
    }
    __syncthreads();
    f32x4 acc[2][4] = {};
    #pragma unroll
    for (int ki=0; ki<KDIM/32; ki++){
      #pragma unroll
      for (int nf=0; nf<4; nf++){
        bf16x8 wfr = *(const bf16x8*)&Ws[(nf*16 + la)*(KDIM+8) + ki*32 + kq*8];
        #pragma unroll
        for (int mf=0; mf<2; mf++)
          acc[mf][nf] = __builtin_amdgcn_mfma_f32_16x16x32_bf16(wfr, af[ki][mf], acc[mf][nf], 0,0,0);
      }
    }
    #pragma unroll
    for (int mf=0; mf<2; mf++){
      #pragma unroll
      for (int nf=0; nf<4; nf++){
        int m    = mw + mf*16 + la;
        int row  = wid*32 + mf*16 + la;
        int colb = nf*16 + kq*4;
        int nb   = n0 + colb;
        f32x4 v = acc[mf][nf];
        if (EPI==1){
          if (nb >= DIN+CONVD){
            if (nb < DPROJ){
              float4 o;
              o.x = softplusf(v[0] + bias[0]); o.y = softplusf(v[1] + bias[1]);
              o.z = softplusf(v[2] + bias[2]); o.w = softplusf(v[3] + bias[3]);
              *(float4*)&of1[(size_t)m*NHEADS] = o;
            }
          } else {
            unsigned int pr[2];
            pr[0] = cvtpk(v[0], v[1]); pr[1] = cvtpk(v[2], v[3]);
            *(u16x4*)&Cb[row*72 + colb] = *(const u16x4*)pr;
          }
        } else if (EPI==2){
          float4 b4 = *(const float4*)&bias[nb];
          unsigned int pr[2];
          pr[0] = cvtpk(geluf(v[0]+b4.x), geluf(v[1]+b4.y));
          pr[1] = cvtpk(geluf(v[2]+b4.z), geluf(v[3]+b4.w));
          *(u16x4*)&Cb[row*72 + colb] = *(const u16x4*)pr;
        } else if (EPI==4){
          unsigned int pr[2];
          pr[0] = cvtpk(v[0]*scv[mf], v[1]*scv[mf]);
          pr[1] = cvtpk(v[2]*scv[mf], v[3]*scv[mf]);
          *(u16x4*)&Cb[row*72 + colb] = *(const u16x4*)pr;
        } else if (EPI==5){
          if (nt == 0){
            float4 b4 = *(const float4*)&bias[colb];
            f32x4 lm; lm[0]=v[0]+b4.x; lm[1]=v[1]+b4.y; lm[2]=v[2]+b4.z; lm[3]=v[3]+b4.w;
            vlm[mf][nf] = lm;
            *(f32x4*)&of1[(size_t)m*64 + colb] = lm;
          } else {
            float4 b4 = *(const float4*)&bias2[colb];
            f32x4 lv; lv[0]=v[0]+b4.x; lv[1]=v[1]+b4.y; lv[2]=v[2]+b4.z; lv[3]=v[3]+b4.w;
            *(f32x4*)&of2[(size_t)m*64 + colb] = lv;
            f32x4 nz = *(const f32x4*)&nzp[(size_t)m*64 + colb];
            f32x4 sp;
            #pragma unroll
            for (int j=0;j<4;j++) sp[j] = fmaf(nz[j], expf(0.5f*lv[j]), vlm[mf][nf][j]);
            *(f32x4*)&of3[(size_t)m*64 + colb] = sp;
          }
        }
      }
    }
    if (EPI!=5){
      __syncthreads();
      #pragma unroll
      for (int j=0; j<4; j++){
        int row = (tid>>3) + j*32;
        int col0 = (tid&7)*8;
        int m = m0 + row;
        int nch = n0 + col0;
        u16x8 val = *(const u16x8*)&Cb[row*72 + col0];
        if (EPI==1){
          if (nch < DIN)            *(u16x8*)&ob1[(size_t)m*DIN + nch] = val;
          else if (nch < DIN+CONVD) *(u16x8*)&ob2[(size_t)m*CONVD + (nch-DIN)] = val;
        } else {
          *(u16x8*)&ob1[(size_t)m*ldc + nch] = val;
        }
      }
    }
    __syncthreads();
  }
}

// ---------------- fused conv helper ------------------------------------------------
__device__ __forceinline__ void conv8(const unsigned short* __restrict__ xraw,
  const float* __restrict__ cwT, const float* __restrict__ cb,
  int seqbase, int t, int ch0, bool full, u16x8* out)
{
  float acc[8];
  float4 b0 = *(const float4*)&cb[ch0];
  float4 b1 = *(const float4*)&cb[ch0+4];
  acc[0]=b0.x; acc[1]=b0.y; acc[2]=b0.z; acc[3]=b0.w;
  acc[4]=b1.x; acc[5]=b1.y; acc[6]=b1.z; acc[7]=b1.w;
  if (full){
    #pragma unroll
    for (int k=0;k<4;k++){
      u16x8 xv = *(const u16x8*)&xraw[(size_t)(seqbase+t-3+k)*CONVD + ch0];
      float4 w0 = *(const float4*)&cwT[k*CONVD + ch0];
      float4 w1 = *(const float4*)&cwT[k*CONVD + ch0 + 4];
      float w[8] = {w0.x,w0.y,w0.z,w0.w,w1.x,w1.y,w1.z,w1.w};
      #pragma unroll
      for (int j=0;j<8;j++) acc[j] = fmaf(w[j], bf2f(xv[j]), acc[j]);
    }
  } else {
    #pragma unroll
    for (int k=0;k<4;k++){
      int tt = t - 3 + k;
      if (tt >= 0){
        u16x8 xv = *(const u16x8*)&xraw[(size_t)(seqbase+tt)*CONVD + ch0];
        float4 w0 = *(const float4*)&cwT[k*CONVD + ch0];
        float4 w1 = *(const float4*)&cwT[k*CONVD + ch0 + 4];
        float w[8] = {w0.x,w0.y,w0.z,w0.w,w1.x,w1.y,w1.z,w1.w};
        #pragma unroll
        for (int j=0;j<8;j++) acc[j] = fmaf(w[j], bf2f(xv[j]), acc[j]);
      }
    }
  }
  unsigned int pr[4];
  pr[0] = cvtpk(siluf(acc[0]), siluf(acc[1]));
  pr[1] = cvtpk(siluf(acc[2]), siluf(acc[3]));
  pr[2] = cvtpk(siluf(acc[4]), siluf(acc[5]));
  pr[3] = cvtpk(siluf(acc[6]), siluf(acc[7]));
  *out = *(const u16x8*)pr;
}

// ---------------- conv for B/C channels (256..287) -> xbc (shared by all heads) ----
__global__ __launch_bounds__(256) void conv_bc_kernel(
  const unsigned short* __restrict__ xraw,
  const float* __restrict__ cwT, const float* __restrict__ cb,
  unsigned short* __restrict__ xbc, int MGi)
{
  int gid = blockIdx.x*256 + threadIdx.x;     // MG2*4
  int m = gid >> 2, part = gid & 3;
  int ch0 = 256 + part*8;
  int t = m & 4095;
  const float* cwTs = cwT + ((m >= MGi) ? 2304 : 0);
  const float* cbs  = cb  + ((m >= MGi) ? 576  : 0);
  u16x8 o;
  conv8(xraw, cwTs, cbs, m - t, t, ch0, t >= 3, &o);
  *(u16x8*)&xbc[(size_t)m*32 + part*8] = o;
}

// ---------------- SSD front: fused x-conv, B from xbc, cumsum, states --------------
__global__ __launch_bounds__(256) void ssd_front(
  const unsigned short* __restrict__ xraw, const unsigned short* __restrict__ xbc,
  const float* __restrict__ dtsp, const float* __restrict__ Alog,
  const float* __restrict__ cwT, const float* __restrict__ cb,
  unsigned short* __restrict__ states_g, float* __restrict__ acs_g,
  float* __restrict__ atot_g, int BGs)
{
  __shared__ __align__(16) unsigned short Xt[64*72];    // [ch][l]
  __shared__ __align__(16) unsigned short Braw[64*24];  // [l][n]
  __shared__ __align__(16) unsigned short Bwt[16*88];   // [n][l]
  __shared__ float acs_s[64], dts_s[64];
  const int bx = blockIdx.x;
  const int h = bx & 3, c = (bx>>2)&63, bl = bx>>8;
  const int tid = threadIdx.x;
  const int tokbase = (bl<<12) + (c<<6);
  const int seqbase = bl<<12;
  const int s1 = (bl >= BGs);
  const float* cwTs = cwT + (s1 ? 2304 : 0);
  const float* cbs  = cb  + (s1 ? 576  : 0);
  const bool full = (c > 0);

  if (tid < 64) {
    float dt = dtsp[(size_t)(tokbase+tid)*NHEADS + h];
    dts_s[tid] = dt;
    float xsc = -__expf(Alog[(s1?8:0) + h]) * dt;
    #pragma unroll
    for (int off=1; off<64; off<<=1){ float v = __shfl_up(xsc, off); if (tid >= off) xsc += v; }
    acs_s[tid] = xsc;
    acs_g[(size_t)bx*64 + tid] = xsc;
  }
  // fused x-conv only: wave gs handles groups {gs, gs+4}
  {
    const int l = tid & 63, gs = tid >> 6;
    const int t = (c<<6) + l;
    #pragma unroll
    for (int i=0;i<2;i++){
      int g = gs + i*4;
      int ch0 = (h<<6)+g*8;
      u16x8 o;
      conv8(xraw, cwTs, cbs, seqbase, t, ch0, full, &o);
      #pragma unroll
      for (int j=0;j<8;j++) Xt[(g*8+j)*72 + l] = o[j];
    }
  }
  // B from xbc (vec8)
  if (tid < 128){
    int l = tid>>1, half = tid&1;
    *(u16x8*)&Braw[l*24 + half*8] = *(const u16x8*)&xbc[(size_t)(tokbase+l)*32 + half*8];
  }
  __syncthreads();
  const float atotv = acs_s[63];
  if (tid==0) atot_g[bx] = atotv;
  if (tid < 128){
    int ch = tid & 15, l0 = (tid>>4)*8;
    float vals[8];
    #pragma unroll
    for (int j=0;j<8;j++){
      int l = l0+j;
      vals[j] = bf2f(Braw[l*24 + ch]) * __expf(atotv - acs_s[l]) * dts_s[l];
    }
    unsigned int pr[4];
    pr[0]=cvtpk(vals[0],vals[1]); pr[1]=cvtpk(vals[2],vals[3]);
    pr[2]=cvtpk(vals[4],vals[5]); pr[3]=cvtpk(vals[6],vals[7]);
    *(u16x8*)&Bwt[ch*88 + l0] = *(const u16x8*)pr;
  }
  __syncthreads();
  const int wid = tid>>6, lane = tid&63;
  const int la = lane&15, kq = lane>>4;
  f32x4 acc = {0.f,0.f,0.f,0.f};
  #pragma unroll
  for (int kt=0; kt<2; kt++){
    bf16x8 a = *(const bf16x8*)&Xt[(wid*16+la)*72 + kt*32+kq*8];
    bf16x8 b = *(const bf16x8*)&Bwt[la*88 + kt*32+kq*8];
    acc = __builtin_amdgcn_mfma_f32_16x16x32_bf16(a, b, acc, 0,0,0);
  }
  size_t base = (size_t)bx<<10;
  {
    unsigned int s01 = cvtpk(acc[0], acc[1]);
    unsigned int s23 = cvtpk(acc[2], acc[3]);
    int p0 = wid*16 + kq*4;
    states_g[base + (size_t)(p0+0)*16 + la] = (unsigned short)s01;
    states_g[base + (size_t)(p0+1)*16 + la] = (unsigned short)(s01>>16);
    states_g[base + (size_t)(p0+2)*16 + la] = (unsigned short)s23;
    states_g[base + (size_t)(p0+3)*16 + la] = (unsigned short)(s23>>16);
  }
}

// ---------------- inter-chunk state scan (bf16 storage, fp32 carry) ----------------
__global__ __launch_bounds__(256) void scan_kernel(unsigned short* __restrict__ states,
  const float* __restrict__ atot)
{
  int gid = blockIdx.x*256 + threadIdx.x;
  int inner = gid & 1023;
  int h = (gid>>10)&3;
  int bl = gid>>12;
  size_t base = (size_t)bl*262144 + h*1024 + inner;
  int abase = bl*256 + h;
  float v[64];
  #pragma unroll
  for (int c2=0;c2<64;c2++) v[c2] = bf2f(states[base + (size_t)c2*4096]);
  float S = 0.0f;
  #pragma unroll
  for (int c2=0;c2<64;c2++){
    states[base + (size_t)c2*4096] = f2bf(S);
    S = __expf(atot[abase + c2*4])*S + v[c2];
  }
}

// ---------------- SSD back: fused x-conv, B/C from xbc, S+Y MFMA, gate, ssq --------
__global__ __launch_bounds__(256) void ssd_back(
  const unsigned short* __restrict__ xraw, const unsigned short* __restrict__ xbc,
  unsigned short* __restrict__ zyf,
  const float* __restrict__ dtsp, const float* __restrict__ acs_g,
  const unsigned short* __restrict__ states, const float* __restrict__ Dp,
  const float* __restrict__ cwT, const float* __restrict__ cb,
  float* __restrict__ ssqp, int BGs)
{
  __shared__ __align__(16) unsigned short U[2*64*72];    // Xt | Sb ; later Yl f32
  __shared__ __align__(16) unsigned short CBS[2*64*24];  // Bp | Cp (stride 24)
  __shared__ float acs_s[64], dts_s[64];
  unsigned short* Xt = U;                  // [ch][l] stride 72
  unsigned short* Sb = U + 64*72;          // Sb[l][s] stride 72
  unsigned short* Bp = CBS;
  unsigned short* Cp = CBS + 64*24;
  float* Yl = (float*)U;                   // [l][p] stride 68
  const int bx = blockIdx.x;
  const int h = bx & 3, c = (bx>>2)&63, bl = bx>>8;
  const int tid = threadIdx.x;
  const int tokbase = (bl<<12) + (c<<6);
  const int seqbase = bl<<12;
  const int s1 = (bl >= BGs);
  const float* cwTs = cwT + (s1 ? 2304 : 0);
  const float* cbs  = cb  + (s1 ? 576  : 0);
  const float Dh = Dp[(s1?8:0) + h];
  const bool full = (c > 0);

  if (tid < 64) {
    dts_s[tid] = dtsp[(size_t)(tokbase+tid)*NHEADS + h];
    acs_s[tid] = acs_g[(size_t)bx*64 + tid];
  }
  // fused x-conv: wave gs handles groups {gs, gs+4}; x -> Xt transposed scalar
  {
    const int l = tid & 63, gs = tid >> 6;
    const int t = (c<<6) + l;
    #pragma unroll
    for (int i=0;i<2;i++){
      int g = gs + i*4;
      int ch0 = (h<<6)+g*8;
      u16x8 o;
      conv8(xraw, cwTs, cbs, seqbase, t, ch0, full, &o);
      #pragma unroll
      for (int j=0;j<8;j++) Xt[(g*8+j)*72 + l] = o[j];
    }
  }
  // B, C from xbc (vec8)
  {
    int l = tid>>2, part = tid&3;
    u16x8 vv = *(const u16x8*)&xbc[(size_t)(tokbase+l)*32 + part*8];
    if (part < 2) *(u16x8*)&Bp[l*24 + part*8] = vv;
    else          *(u16x8*)&Cp[l*24 + (part-2)*8] = vv;
  }
  __syncthreads();

  const int wid = tid>>6, lane = tid&63;
  const int la = lane&15, kq = lane>>4;
  const int L0 = wid*16;
  const f32x4 zero4 = {0.f,0.f,0.f,0.f};
  const bf16x8 zfrag = {0,0,0,0,0,0,0,0};

  // CB = C·B^T (K=32, upper-half fragments zero) -> mask/scale, fold D -> Sb bf16
  {
    bf16x8 a = (kq<2) ? *(const bf16x8*)&Cp[(L0+la)*24 + kq*8] : zfrag;
    f32x4 cbacc[4];
    #pragma unroll
    for (int nf=0; nf<4; nf++){
      bf16x8 b = (kq<2) ? *(const bf16x8*)&Bp[(nf*16+la)*24 + kq*8] : zfrag;
      cbacc[nf] = __builtin_amdgcn_mfma_f32_16x16x32_bf16(a, b, zero4, 0,0,0);
    }
    #pragma unroll
    for (int nf=0; nf<4; nf++){
      int s = nf*16 + la;
      float vv[4];
      #pragma unroll
      for (int r=0; r<4; r++){
        int l = L0 + kq*4 + r;
        float v = 0.f;
        if (s <= l) v = __expf(acs_s[l]-acs_s[s])*dts_s[s]*cbacc[nf][r];
        if (s == l) v += Dh;
        vv[r] = v;
      }
      unsigned int p01 = cvtpk(vv[0], vv[1]);
      unsigned int p23 = cvtpk(vv[2], vv[3]);
      int lb = L0 + kq*4;
      Sb[(lb+0)*72 + s] = (unsigned short)p01;
      Sb[(lb+1)*72 + s] = (unsigned short)(p01>>16);
      Sb[(lb+2)*72 + s] = (unsigned short)p23;
      Sb[(lb+3)*72 + s] = (unsigned short)(p23>>16);
    }
  }
  // Y_off = C·states^T (states fragments from global), scale exp(acs[l])
  f32x4 ya[4];
  {
    bf16x8 a = (kq<2) ? *(const bf16x8*)&Cp[(L0+la)*24 + kq*8] : zfrag;
    #pragma unroll
    for (int nf=0; nf<4; nf++){
      bf16x8 b = (kq<2) ? *(const bf16x8*)&states[((size_t)bx<<10) + (size_t)(nf*16+la)*16 + kq*8] : zfrag;
      ya[nf] = __builtin_amdgcn_mfma_f32_16x16x32_bf16(a, b, zero4, 0,0,0);
    }
    float eal[4];
    #pragma unroll
    for (int r=0; r<4; r++) eal[r] = __expf(acs_s[L0 + kq*4 + r]);
    #pragma unroll
    for (int nf=0; nf<4; nf++)
      #pragma unroll
      for (int r=0; r<4; r++) ya[nf][r] *= eal[r];
  }
  // Y_diag += Sb·Xt^T (K=64); A-operand reads only own-wave Sb rows
  #pragma unroll
  for (int kt=0; kt<2; kt++){
    bf16x8 a = *(const bf16x8*)&Sb[(L0+la)*72 + kt*32+kq*8];
    #pragma unroll
    for (int nf=0; nf<4; nf++){
      bf16x8 b = *(const bf16x8*)&Xt[(nf*16+la)*72 + kt*32+kq*8];
      ya[nf] = __builtin_amdgcn_mfma_f32_16x16x32_bf16(a, b, ya[nf], 0,0,0);
    }
  }
  __syncthreads();   // all waves done reading Xt/Sb -> Yl alias safe
  #pragma unroll
  for (int nf=0; nf<4; nf++){
    #pragma unroll
    for (int r=0; r<4; r++){
      int l = L0 + kq*4 + r, p = nf*16 + la;
      Yl[l*68 + p] = ya[nf][r];
    }
  }
  __syncthreads();
  #pragma unroll
  for (int i=0;i<2;i++){
    int u = tid + (i<<8);
    int l = u>>3, g = u&7;
    size_t gidx = (size_t)(tokbase+l)*DIN + (h<<6) + g*8;
    u16x8 z8 = *(const u16x8*)&zyf[gidx];
    float yv[8];
    float ps = 0.f;
    #pragma unroll
    for (int j=0;j<8;j++){
      float y = Yl[l*68 + g*8 + j];
      float zv = bf2f(z8[j]);
      yv[j] = y * zv * sigm(zv);
      ps = fmaf(yv[j], yv[j], ps);
    }
    unsigned int pr[4];
    pr[0]=cvtpk(yv[0],yv[1]); pr[1]=cvtpk(yv[2],yv[3]);
    pr[2]=cvtpk(yv[4],yv[5]); pr[3]=cvtpk(yv[6],yv[7]);
    *(u16x8*)&zyf[gidx] = *(const u16x8*)pr;
    ps += __shfl_xor(ps, 1); ps += __shfl_xor(ps, 2); ps += __shfl_xor(ps, 4);
    if (g == 0) ssqp[(size_t)(tokbase+l)*NHEADS + h] = ps;
  }
}

// ---------------- predgate -------------------------------------------------------
__global__ __launch_bounds__(256) void predgate_kernel(
  const unsigned short* __restrict__ fused, const float* __restrict__ sample,
  const unsigned short* __restrict__ gwb, const float* __restrict__ gb,
  const float* __restrict__ ow, const float* __restrict__ ob,
  const float* __restrict__ rg, float* __restrict__ pred)
{
  __shared__ __align__(16) unsigned short Ws[64*72];
  __shared__ __align__(16) float Gp[128*68];
  const int tid = threadIdx.x;
  const int m0 = blockIdx.x<<7;
  const int wid = tid>>6, lane = tid&63;
  const int la = lane&15, kq = lane>>4;
  const int mw = m0 + wid*32;

  bf16x8 af[2][2];
  #pragma unroll
  for (int ki=0; ki<2; ki++){
    int k = ki*32 + kq*8;
    #pragma unroll
    for (int mf=0; mf<2; mf++){
      int row = mw + mf*16 + la;
      float4 s0 = *(const float4*)&sample[(size_t)row*64 + k];
      float4 s1 = *(const float4*)&sample[(size_t)row*64 + k + 4];
      unsigned int pr[4];
      pr[0]=cvtpk(s0.x,s0.y); pr[1]=cvtpk(s0.z,s0.w);
      pr[2]=cvtpk(s1.x,s1.y); pr[3]=cvtpk(s1.z,s1.w);
      af[ki][mf] = *(const bf16x8*)pr;
    }
  }
  const float ob0 = ob[0];
  const int prow = tid>>1, phalf = tid&1;
  float rs = 0.f;

  #pragma unroll
  for (int nt=0; nt<2; nt++){
    int n0 = nt<<6;
    #pragma unroll
    for (int i=0;i<2;i++){
      int slot = tid + (i<<8);
      int row = slot>>3, g = slot&7;
      *(u16x8*)&Ws[row*72 + g*8] = *(const u16x8*)&gwb[(size_t)(n0+row)*64 + g*8];
    }
    __syncthreads();
    f32x4 acc[2][4] = {};
    #pragma unroll
    for (int ki=0; ki<2; ki++){
      #pragma unroll
      for (int nf=0; nf<4; nf++){
        bf16x8 bfr = *(const bf16x8*)&Ws[(nf*16 + la)*72 + ki*32 + kq*8];
        #pragma unroll
        for (int mf=0; mf<2; mf++)
          acc[mf][nf] = __builtin_amdgcn_mfma_f32_16x16x32_bf16(af[ki][mf], bfr, acc[mf][nf], 0,0,0);
      }
    }
    #pragma unroll
    for (int mf=0; mf<2; mf++){
      #pragma unroll
      for (int nf=0; nf<4; nf++){
        #pragma unroll
        for (int r=0; r<4; r++){
          int row = wid*32 + mf*16 + kq*4 + r;
          int col = nf*16 + la;
          int n = n0 + col;
          Gp[row*68 + col] = sigm(acc[mf][nf][r] + gb[n]) * ow[n];
        }
      }
    }
    __syncthreads();
    #pragma unroll
    for (int q=0; q<4; q++){
      int col0 = phalf*32 + q*8;
      u16x8 f8 = *(const u16x8*)&fused[(size_t)(m0+prow)*128 + n0 + col0];
      float4 g0 = *(const float4*)&Gp[prow*68 + col0];
      float4 g1 = *(const float4*)&Gp[prow*68 + col0 + 4];
      rs = fmaf(bf2f(f8[0]), g0.x, rs); rs = fmaf(bf2f(f8[1]), g0.y, rs);
      rs = fmaf(bf2f(f8[2]), g0.z, rs); rs = fmaf(bf2f(f8[3]), g0.w, rs);
      rs = fmaf(bf2f(f8[4]), g1.x, rs); rs = fmaf(bf2f(f8[5]), g1.y, rs);
      rs = fmaf(bf2f(f8[6]), g1.z, rs); rs = fmaf(bf2f(f8[7]), g1.w, rs);
    }
    __syncthreads();
  }
  rs += __shfl_xor(rs, 1);
  if (phalf == 0){
    int m = m0 + prow;
    pred[m] = (rs + ob0) * sigm(rg[m & 4095]);
  }
}

extern "C" void kernel_launch(void* const* d_in, const int* in_sizes, int n_in,
                              void* d_out, int out_size, void* d_ws, size_t ws_size,
                              hipStream_t stream)
{
  const float* expr      = (const float*)d_in[0];
  const float* noise     = (const float*)d_in[1];
  const float* expr_w    = (const float*)d_in[2];
  const float* expr_b    = (const float*)d_in[3];
  const float* in_proj_w = (const float*)d_in[4];
  const float* conv_w    = (const float*)d_in[5];
  const float* conv_b    = (const float*)d_in[6];
  const float* dt_bias   = (const float*)d_in[7];
  const float* A_log     = (const float*)d_in[8];
  const float* D_par     = (const float*)d_in[9];
  const float* norm_w    = (const float*)d_in[10];
  const float* out_proj_w= (const float*)d_in[11];
  const float* fusion_w  = (const float*)d_in[12];
  const float* fusion_b  = (const float*)d_in[13];
  const float* lm_w      = (const float*)d_in[14];
  const float* lm_b      = (const float*)d_in[15];
  const float* lv_w      = (const float*)d_in[16];
  const float* lv_b      = (const float*)d_in[17];
  const float* gate_w    = (const float*)d_in[18];
  const float* gate_b    = (const float*)d_in[19];
  const float* outp_w    = (const float*)d_in[20];
  const float* outp_b    = (const float*)d_in[21];
  const float* reg_gate  = (const float*)d_in[22];

  const size_t WBYTES = 956416;
  const int IMAX = 0x7fffffff;
  int BG = 0;
  const int cands[5] = {16, 8, 4, 2, 1};
  for (int ci = 0; ci < 5; ci++) {
    int c2 = cands[ci];
    size_t MG2c = (size_t)2 * c2 * LSEQ;
    size_t need = WBYTES + MG2c*1584 + (size_t)c2*2048 + 256;
    if (need <= ws_size) { BG = c2; break; }
  }
  if (!BG) return;
  const size_t MG  = (size_t)BG * LSEQ;
  const size_t MG2 = 2*MG;

  unsigned short* wip = (unsigned short*)d_ws;
  unsigned short* wop = wip + 280576;
  unsigned short* wfu = wop + 131072;
  unsigned short* wlm = wfu + 32768;
  unsigned short* wlv = wlm + 8192;
  unsigned short* wgw = wlv + 8192;
  float* cwT   = (float*)(wgw + 8192);
  float* dtsp  = (float*)((char*)d_ws + WBYTES);
  float* acs   = dtsp + MG2*4;
  float* atot  = acs  + MG2*4;
  float* ssqp  = atot + (size_t)2*BG*256;
  unsigned short* statesb = (unsigned short*)(ssqp + MG2*4);
  unsigned short* xbc   = statesb + MG2*64;         // MG2*32 (conv'd B/C)
  unsigned short* zyf   = xbc + MG2*32;
  unsigned short* xrawb = zyf + MG2*256;
  unsigned short* act   = xrawb + MG2*288;
  unsigned short* actA  = act;
  unsigned short* actB  = act + MG*128;
  unsigned short* fusedbf = zyf;

  float* out_pred_g = (float*)d_out;
  float* out_lm_g   = out_pred_g + (size_t)16*LSEQ;
  float* out_lv_g   = out_lm_g   + (size_t)16*LSEQ*LAT;
  float* out_samp_g = out_lv_g   + (size_t)16*LSEQ*LAT;

  cvt_kernel<<<(280576+255)/256, 256, 0, stream>>>(in_proj_w, wip, 280576);
  cvt_nw_kernel<<<131072/256,    256, 0, stream>>>(out_proj_w, norm_w, wop, 131072);
  cvt_kernel<<<32768/256,        256, 0, stream>>>(fusion_w, wfu, 32768);
  cvt_kernel<<<8192/256,         256, 0, stream>>>(lm_w, wlm, 8192);
  cvt_kernel<<<8192/256,         256, 0, stream>>>(lv_w, wlv, 8192);
  cvt_kernel<<<8192/256,         256, 0, stream>>>(gate_w, wgw, 8192);
  cvt_cw_kernel<<<(4608+255)/256, 256, 0, stream>>>(conv_w, cwT);

  for (int b0 = 0; b0 < 16; b0 += BG) {
    float* out_pred = out_pred_g + (size_t)b0*LSEQ;
    float* out_lm   = out_lm_g   + (size_t)b0*LSEQ*LAT;
    float* out_lv   = out_lv_g   + (size_t)b0*LSEQ*LAT;
    float* out_samp = out_samp_g + (size_t)b0*LSEQ*LAT;
    const float* nz = noise      + (size_t)b0*LSEQ*LAT;

    embed_kernel<<<(MG*128)/256, 256, 0, stream>>>(expr + (size_t)b0*LSEQ, expr_w, expr_b, actA, actB);

    for (int p = 0; p < 2; p++) {
      const unsigned short* Wi = wip + (size_t)p*DPROJ*HMOD;
      const unsigned short* Wo = wop + (size_t)p*HMOD*DIN;
      const float* cwTl = cwT + (size_t)p*1152;
      const float* cb   = conv_b + (size_t)p*CONVD;
      const float* dtb  = dt_bias + (size_t)p*NHEADS;
      const float* Al   = A_log + (size_t)p*NHEADS;
      const float* Dl   = D_par + (size_t)p*NHEADS;

      gemm3<128,3,1><<<dim3(MG2/128, 3), 256, 0, stream>>>(act, nullptr, Wi, dtb, nullptr, nullptr,
        zyf, xrawb, dtsp, nullptr, nullptr, nullptr, DPROJ, 0, (int)MG, 2*DPROJ*HMOD, 2*NHEADS);
      conv_bc_kernel<<<(MG2*4)/256, 256, 0, stream>>>(xrawb, cwTl, cb, xbc, (int)MG);
      ssd_front<<<2*BG*256, 256, 0, stream>>>(xrawb, xbc, dtsp, Al, cwTl, cb, statesb, acs, atot, BG);
      scan_kernel<<<(2*BG*LSEQ)/256, 256, 0, stream>>>(statesb, atot);
      ssd_back<<<2*BG*256, 256, 0, stream>>>(xrawb, xbc, zyf, dtsp, acs, statesb, Dl, cwTl, cb, ssqp, BG);
      gemm3<256,1,4><<<dim3(MG2/128, 2), 256, 0, stream>>>(zyf, nullptr, Wo, nullptr, nullptr, ssqp,
        act, nullptr, nullptr, nullptr, nullptr, nullptr, HMOD, HMOD, (int)MG, 2*HMOD*DIN, 0);
    }

    gemm3<256,1,2><<<dim3(MG/128, 2), 256, 0, stream>>>(actA, actB, wfu, fusion_b, nullptr, nullptr,
      fusedbf, nullptr, nullptr, nullptr, nullptr, nullptr, HMOD, HMOD, IMAX, 0, 0);
    gemm3<128,2,5><<<dim3(MG/128, 1), 256, 0, stream>>>(fusedbf, nullptr, wlm, lm_b, lv_b, nullptr,
      nullptr, nullptr, out_lm, out_lv, nz, out_samp, 128, LAT, IMAX, 0, 0);
    predgate_kernel<<<MG/128, 256, 0, stream>>>(fusedbf, out_samp, wgw, gate_b, outp_w, outp_b, reg_gate, out_pred);
  }
}

// Round 19
// 575.030 us; speedup vs baseline: 1.0479x; 1.0122x over previous
//
#include <hip/hip_runtime.h>
#include <math.h>

#define HMOD 128
#define DIN 256
#define NHEADS 4
#define HD 64
#define DSTATE 16
#define NCH 64
#define CONVD 288
#define DPROJ 548
#define LAT 64
#define LSEQ 4096

typedef __attribute__((ext_vector_type(8))) short bf16x8;
typedef __attribute__((ext_vector_type(4))) float f32x4;
typedef __attribute__((ext_vector_type(8))) unsigned short u16x8;
typedef __attribute__((ext_vector_type(4))) unsigned short u16x4;

__device__ __forceinline__ float sigm(float x){ return 1.0f/(1.0f+__expf(-x)); }
__device__ __forceinline__ float siluf(float x){ return x/(1.0f+__expf(-x)); }
__device__ __forceinline__ float softplusf(float x){ return (x>20.0f)? x : log1pf(expf(x)); }
__device__ __forceinline__ float geluf(float x){ return 0.5f*x*(1.0f+erff(x*0.70710678118654752440f)); }
__device__ __forceinline__ unsigned short f2bf(float x){
  unsigned int u = __float_as_uint(x);
  return (unsigned short)((u + 0x7FFFu + ((u>>16)&1u)) >> 16);
}
__device__ __forceinline__ float bf2f(unsigned short h){
  return __uint_as_float(((unsigned int)h)<<16);
}
__device__ __forceinline__ unsigned int cvtpk(float a, float b){
  unsigned int r;
  asm("v_cvt_pk_bf16_f32 %0, %1, %2" : "=v"(r) : "v"(a), "v"(b));
  return r;
}

// ---------------- weight conversion ----------------
__global__ __launch_bounds__(256) void cvt_kernel(const float* __restrict__ in,
  unsigned short* __restrict__ out, int n)
{
  int i = blockIdx.x*256 + threadIdx.x;
  if (i < n) out[i] = f2bf(in[i]);
}
__global__ __launch_bounds__(256) void cvt_nw_kernel(const float* __restrict__ in,
  const float* __restrict__ nw, unsigned short* __restrict__ out, int n)
{
  int i = blockIdx.x*256 + threadIdx.x;
  if (i < n){
    int k = i & 255;
    int li = i >> 15;
    out[i] = f2bf(in[i]*nw[li*256 + k]);
  }
}
__global__ __launch_bounds__(256) void cvt_cw_kernel(const float* __restrict__ in,
  float* __restrict__ out)
{
  int i = blockIdx.x*256 + threadIdx.x;
  if (i < 4608){
    int li = i/1152, r = i - li*1152;
    int ch = r>>2, k = r&3;
    out[li*1152 + k*CONVD + ch] = in[i];
  }
}

// ---------------- embedding ----------------
__global__ __launch_bounds__(256) void embed_kernel(const float* __restrict__ expr,
    const float* __restrict__ ew, const float* __restrict__ eb,
    unsigned short* __restrict__ actA, unsigned short* __restrict__ actB)
{
  int gid = blockIdx.x*256 + threadIdx.x;
  int m = gid >> 7, hh = gid & 127;
  int bl = m >> 12, g = m & 4095;
  unsigned short v = f2bf(expr[m]*ew[hh] + eb[hh]);
  actA[gid] = v;
  actB[(size_t)(((bl<<12) | (4095-g))<<7) + hh] = v;
}

// ---------------- MFMA GEMM (LDS-staged W, swapped operands, dual-stream) --------
template<int KDIM, int NT, int EPI>
__global__ __launch_bounds__(256) void gemm3(
    const unsigned short* __restrict__ A,
    const unsigned short* __restrict__ A2,
    const unsigned short* __restrict__ Wb,
    const float* __restrict__ bias,
    const float* __restrict__ bias2,
    const float* __restrict__ ssqp,
    unsigned short* __restrict__ ob1,
    unsigned short* __restrict__ ob2,
    float* __restrict__ of1,
    float* __restrict__ of2,
    const float* __restrict__ nzp,
    float* __restrict__ of3,
    int N, int ldc, int mhalf, int wsel, int bsel)
{
  __shared__ unsigned short Ws[64*(KDIM+8)];
  __shared__ __align__(16) unsigned short Cb[(EPI==5) ? 8 : 128*72];
  const int tid = threadIdx.x;
  const int m0 = blockIdx.x<<7;
  if (m0 >= mhalf){ Wb += wsel; bias += bsel; }
  const int wid = tid>>6, lane = tid&63;
  const int la = lane&15, kq = lane>>4;
  const int mw = m0 + wid*32;

  bf16x8 af[KDIM/32][2];
  #pragma unroll
  for (int ki=0; ki<KDIM/32; ki++){
    int k = ki*32 + kq*8;
    #pragma unroll
    for (int mf=0; mf<2; mf++){
      int row = mw + mf*16 + la;
      const unsigned short* src;
      if (EPI==2){
        if (k < 128) src = A + (size_t)row*128 + k;
        else { int bl2=row>>12, t=row&4095; src = A2 + (size_t)(((bl2<<12)|(4095-t)))*128 + (k-128); }
      } else {
        src = A + (size_t)row*KDIM + k;
      }
      af[ki][mf] = *(const bf16x8*)src;
    }
  }
  float scv[2];
  if (EPI==4){
    #pragma unroll
    for (int mf=0; mf<2; mf++){
      int m = mw + mf*16 + la;
      float4 s4 = *(const float4*)&ssqp[m*4];
      scv[mf] = rsqrtf((s4.x+s4.y+s4.z+s4.w)*(1.0f/256.0f) + 1e-5f);
    }
  }
  f32x4 vlm[2][4];

  const int KD8 = KDIM/8;
  for (int nt=0; nt<NT; nt++){
    int n0 = (blockIdx.y*NT + nt)<<6;
    for (int ci = tid; ci < 64*KD8; ci += 256){
      int row = ci/KD8, kc = (ci - row*KD8)*8;
      int n = n0 + row;
      bf16x8 v = {0,0,0,0,0,0,0,0};
      if (n < N) v = *(const bf16x8*)&Wb[(size_t)n*KDIM + kc];
      *(bf16x8*)&Ws[row*(KDIM+8) + kc] = v;
    }
    __syncthreads();
    f32x4 acc[2][4] = {};
    #pragma unroll
    for (int ki=0; ki<KDIM/32; ki++){
      #pragma unroll
      for (int nf=0; nf<4; nf++){
        bf16x8 wfr = *(const bf16x8*)&Ws[(nf*16 + la)*(KDIM+8) + ki*32 + kq*8];
        #pragma unroll
        for (int mf=0; mf<2; mf++)
          acc[mf][nf] = __builtin_amdgcn_mfma_f32_16x16x32_bf16(wfr, af[ki][mf], acc[mf][nf], 0,0,0);
      }
    }
    #pragma unroll
    for (int mf=0; mf<2; mf++){
      #pragma unroll
      for (int nf=0; nf<4; nf++){
        int m    = mw + mf*16 + la;
        int row  = wid*32 + mf*16 + la;
        int colb = nf*16 + kq*4;
        int nb   = n0 + colb;
        f32x4 v = acc[mf][nf];
        if (EPI==1){
          if (nb >= DIN+CONVD){
            if (nb < DPROJ){
              float4 o;
              o.x = softplusf(v[0] + bias[0]); o.y = softplusf(v[1] + bias[1]);
              o.z = softplusf(v[2] + bias[2]); o.w = softplusf(v[3] + bias[3]);
              *(float4*)&of1[(size_t)m*NHEADS] = o;
            }
          } else {
            unsigned int pr[2];
            pr[0] = cvtpk(v[0], v[1]); pr[1] = cvtpk(v[2], v[3]);
            *(u16x4*)&Cb[row*72 + colb] = *(const u16x4*)pr;
          }
        } else if (EPI==2){
          float4 b4 = *(const float4*)&bias[nb];
          unsigned int pr[2];
          pr[0] = cvtpk(geluf(v[0]+b4.x), geluf(v[1]+b4.y));
          pr[1] = cvtpk(geluf(v[2]+b4.z), geluf(v[3]+b4.w));
          *(u16x4*)&Cb[row*72 + colb] = *(const u16x4*)pr;
        } else if (EPI==4){
          unsigned int pr[2];
          pr[0] = cvtpk(v[0]*scv[mf], v[1]*scv[mf]);
          pr[1] = cvtpk(v[2]*scv[mf], v[3]*scv[mf]);
          *(u16x4*)&Cb[row*72 + colb] = *(const u16x4*)pr;
        } else if (EPI==5){
          if (nt == 0){
            float4 b4 = *(const float4*)&bias[colb];
            f32x4 lm; lm[0]=v[0]+b4.x; lm[1]=v[1]+b4.y; lm[2]=v[2]+b4.z; lm[3]=v[3]+b4.w;
            vlm[mf][nf] = lm;
            *(f32x4*)&of1[(size_t)m*64 + colb] = lm;
          } else {
            float4 b4 = *(const float4*)&bias2[colb];
            f32x4 lv; lv[0]=v[0]+b4.x; lv[1]=v[1]+b4.y; lv[2]=v[2]+b4.z; lv[3]=v[3]+b4.w;
            *(f32x4*)&of2[(size_t)m*64 + colb] = lv;
            f32x4 nz = *(const f32x4*)&nzp[(size_t)m*64 + colb];
            f32x4 sp;
            #pragma unroll
            for (int j=0;j<4;j++) sp[j] = fmaf(nz[j], expf(0.5f*lv[j]), vlm[mf][nf][j]);
            *(f32x4*)&of3[(size_t)m*64 + colb] = sp;
          }
        }
      }
    }
    if (EPI!=5){
      __syncthreads();
      #pragma unroll
      for (int j=0; j<4; j++){
        int row = (tid>>3) + j*32;
        int col0 = (tid&7)*8;
        int m = m0 + row;
        int nch = n0 + col0;
        u16x8 val = *(const u16x8*)&Cb[row*72 + col0];
        if (EPI==1){
          if (nch < DIN)            *(u16x8*)&ob1[(size_t)m*DIN + nch] = val;
          else if (nch < DIN+CONVD) *(u16x8*)&ob2[(size_t)m*CONVD + (nch-DIN)] = val;
        } else {
          *(u16x8*)&ob1[(size_t)m*ldc + nch] = val;
        }
      }
    }
    __syncthreads();
  }
}

// ---------------- fused conv helper ------------------------------------------------
__device__ __forceinline__ void conv8(const unsigned short* __restrict__ xraw,
  const float* __restrict__ cwT, const float* __restrict__ cb,
  int seqbase, int t, int ch0, bool full, u16x8* out)
{
  float acc[8];
  float4 b0 = *(const float4*)&cb[ch0];
  float4 b1 = *(const float4*)&cb[ch0+4];
  acc[0]=b0.x; acc[1]=b0.y; acc[2]=b0.z; acc[3]=b0.w;
  acc[4]=b1.x; acc[5]=b1.y; acc[6]=b1.z; acc[7]=b1.w;
  if (full){
    #pragma unroll
    for (int k=0;k<4;k++){
      u16x8 xv = *(const u16x8*)&xraw[(size_t)(seqbase+t-3+k)*CONVD + ch0];
      float4 w0 = *(const float4*)&cwT[k*CONVD + ch0];
      float4 w1 = *(const float4*)&cwT[k*CONVD + ch0 + 4];
      float w[8] = {w0.x,w0.y,w0.z,w0.w,w1.x,w1.y,w1.z,w1.w};
      #pragma unroll
      for (int j=0;j<8;j++) acc[j] = fmaf(w[j], bf2f(xv[j]), acc[j]);
    }
  } else {
    #pragma unroll
    for (int k=0;k<4;k++){
      int tt = t - 3 + k;
      if (tt >= 0){
        u16x8 xv = *(const u16x8*)&xraw[(size_t)(seqbase+tt)*CONVD + ch0];
        float4 w0 = *(const float4*)&cwT[k*CONVD + ch0];
        float4 w1 = *(const float4*)&cwT[k*CONVD + ch0 + 4];
        float w[8] = {w0.x,w0.y,w0.z,w0.w,w1.x,w1.y,w1.z,w1.w};
        #pragma unroll
        for (int j=0;j<8;j++) acc[j] = fmaf(w[j], bf2f(xv[j]), acc[j]);
      }
    }
  }
  unsigned int pr[4];
  pr[0] = cvtpk(siluf(acc[0]), siluf(acc[1]));
  pr[1] = cvtpk(siluf(acc[2]), siluf(acc[3]));
  pr[2] = cvtpk(siluf(acc[4]), siluf(acc[5]));
  pr[3] = cvtpk(siluf(acc[6]), siluf(acc[7]));
  *out = *(const u16x8*)pr;
}

// ---------------- conv for B/C channels (256..287) -> xbc --------------------------
__global__ __launch_bounds__(256) void conv_bc_kernel(
  const unsigned short* __restrict__ xraw,
  const float* __restrict__ cwT, const float* __restrict__ cb,
  unsigned short* __restrict__ xbc, int MGi)
{
  int gid = blockIdx.x*256 + threadIdx.x;     // MG2*4
  int m = gid >> 2, part = gid & 3;
  int ch0 = 256 + part*8;
  int t = m & 4095;
  const float* cwTs = cwT + ((m >= MGi) ? 2304 : 0);
  const float* cbs  = cb  + ((m >= MGi) ? 576  : 0);
  u16x8 o;
  conv8(xraw, cwTs, cbs, m - t, t, ch0, t >= 3, &o);
  *(u16x8*)&xbc[(size_t)m*32 + part*8] = o;
}

// ---------------- SSD front: fused x-conv, B from xbc, cumsum, states --------------
__global__ __launch_bounds__(256) void ssd_front(
  const unsigned short* __restrict__ xraw, const unsigned short* __restrict__ xbc,
  const float* __restrict__ dtsp, const float* __restrict__ Alog,
  const float* __restrict__ cwT, const float* __restrict__ cb,
  unsigned short* __restrict__ states_g, float* __restrict__ acs_g,
  float* __restrict__ atot_g, int BGs)
{
  __shared__ __align__(16) unsigned short Xt[64*72];    // [ch][l]
  __shared__ __align__(16) unsigned short Braw[64*24];  // [l][n]
  __shared__ __align__(16) unsigned short Bwt[16*88];   // [n][l]
  __shared__ float acs_s[64], endt_s[64];
  const int bx = blockIdx.x;
  const int h = bx & 3, c = (bx>>2)&63, bl = bx>>8;
  const int tid = threadIdx.x;
  const int tokbase = (bl<<12) + (c<<6);
  const int seqbase = bl<<12;
  const int s1 = (bl >= BGs);
  const float* cwTs = cwT + (s1 ? 2304 : 0);
  const float* cbs  = cb  + (s1 ? 576  : 0);
  const bool full = (c > 0);

  if (tid < 64) {
    float dt = dtsp[(size_t)(tokbase+tid)*NHEADS + h];
    float xsc = -__expf(Alog[(s1?8:0) + h]) * dt;
    #pragma unroll
    for (int off=1; off<64; off<<=1){ float v = __shfl_up(xsc, off); if (tid >= off) xsc += v; }
    acs_s[tid] = xsc;
    endt_s[tid] = __expf(-xsc)*dt;
    acs_g[(size_t)bx*64 + tid] = xsc;
  }
  // fused x-conv: wave gs handles groups {gs, gs+4}
  {
    const int l = tid & 63, gs = tid >> 6;
    const int t = (c<<6) + l;
    #pragma unroll
    for (int i=0;i<2;i++){
      int g = gs + i*4;
      int ch0 = (h<<6)+g*8;
      u16x8 o;
      conv8(xraw, cwTs, cbs, seqbase, t, ch0, full, &o);
      #pragma unroll
      for (int j=0;j<8;j++) Xt[(g*8+j)*72 + l] = o[j];
    }
  }
  // B from xbc (vec8)
  if (tid < 128){
    int l = tid>>1, half = tid&1;
    *(u16x8*)&Braw[l*24 + half*8] = *(const u16x8*)&xbc[(size_t)(tokbase+l)*32 + half*8];
  }
  __syncthreads();
  const float atotv = acs_s[63];
  if (tid==0) atot_g[bx] = atotv;
  if (tid < 128){
    int ch = tid & 15, l0 = (tid>>4)*8;
    const float eat = __expf(atotv);
    float vals[8];
    #pragma unroll
    for (int j=0;j<8;j++){
      int l = l0+j;
      vals[j] = bf2f(Braw[l*24 + ch]) * (eat * endt_s[l]);
    }
    unsigned int pr[4];
    pr[0]=cvtpk(vals[0],vals[1]); pr[1]=cvtpk(vals[2],vals[3]);
    pr[2]=cvtpk(vals[4],vals[5]); pr[3]=cvtpk(vals[6],vals[7]);
    *(u16x8*)&Bwt[ch*88 + l0] = *(const u16x8*)pr;
  }
  __syncthreads();
  const int wid = tid>>6, lane = tid&63;
  const int la = lane&15, kq = lane>>4;
  f32x4 acc = {0.f,0.f,0.f,0.f};
  #pragma unroll
  for (int kt=0; kt<2; kt++){
    bf16x8 a = *(const bf16x8*)&Xt[(wid*16+la)*72 + kt*32+kq*8];
    bf16x8 b = *(const bf16x8*)&Bwt[la*88 + kt*32+kq*8];
    acc = __builtin_amdgcn_mfma_f32_16x16x32_bf16(a, b, acc, 0,0,0);
  }
  size_t base = (size_t)bx<<10;
  {
    unsigned int s01 = cvtpk(acc[0], acc[1]);
    unsigned int s23 = cvtpk(acc[2], acc[3]);
    int p0 = wid*16 + kq*4;
    states_g[base + (size_t)(p0+0)*16 + la] = (unsigned short)s01;
    states_g[base + (size_t)(p0+1)*16 + la] = (unsigned short)(s01>>16);
    states_g[base + (size_t)(p0+2)*16 + la] = (unsigned short)s23;
    states_g[base + (size_t)(p0+3)*16 + la] = (unsigned short)(s23>>16);
  }
}

// ---------------- inter-chunk state scan (bf16 storage, fp32 carry) ----------------
__global__ __launch_bounds__(256) void scan_kernel(unsigned short* __restrict__ states,
  const float* __restrict__ atot)
{
  int gid = blockIdx.x*256 + threadIdx.x;
  int inner = gid & 1023;
  int h = (gid>>10)&3;
  int bl = gid>>12;
  size_t base = (size_t)bl*262144 + h*1024 + inner;
  int abase = bl*256 + h;
  float v[64];
  #pragma unroll
  for (int c2=0;c2<64;c2++) v[c2] = bf2f(states[base + (size_t)c2*4096]);
  float S = 0.0f;
  #pragma unroll
  for (int c2=0;c2<64;c2++){
    states[base + (size_t)c2*4096] = f2bf(S);
    S = __expf(atot[abase + c2*4])*S + v[c2];
  }
}

// ---------------- SSD back: factored exp, B/C from xbc, S+Y MFMA, gate, ssq --------
__global__ __launch_bounds__(256) void ssd_back(
  const unsigned short* __restrict__ xraw, const unsigned short* __restrict__ xbc,
  unsigned short* __restrict__ zyf,
  const float* __restrict__ dtsp, const float* __restrict__ acs_g,
  const unsigned short* __restrict__ states, const float* __restrict__ Dp,
  const float* __restrict__ cwT, const float* __restrict__ cb,
  float* __restrict__ ssqp, int BGs)
{
  __shared__ __align__(16) unsigned short U[2*64*72];    // Xt | Sb ; later Yl f32
  __shared__ __align__(16) unsigned short CBS[2*64*24];  // Bp | Cp (stride 24)
  __shared__ float exps_s[64], endt_s[64];
  unsigned short* Xt = U;                  // [ch][l] stride 72
  unsigned short* Sb = U + 64*72;          // Sb[l][s] stride 72
  unsigned short* Bp = CBS;
  unsigned short* Cp = CBS + 64*24;
  float* Yl = (float*)U;                   // [l][p] stride 68
  const int bx = blockIdx.x;
  const int h = bx & 3, c = (bx>>2)&63, bl = bx>>8;
  const int tid = threadIdx.x;
  const int tokbase = (bl<<12) + (c<<6);
  const int seqbase = bl<<12;
  const int s1 = (bl >= BGs);
  const float* cwTs = cwT + (s1 ? 2304 : 0);
  const float* cbs  = cb  + (s1 ? 576  : 0);
  const float Dh = Dp[(s1?8:0) + h];
  const bool full = (c > 0);

  if (tid < 64) {
    float dt = dtsp[(size_t)(tokbase+tid)*NHEADS + h];
    float a  = acs_g[(size_t)bx*64 + tid];
    exps_s[tid] = __expf(a);
    endt_s[tid] = __expf(-a)*dt;
  }
  // fused x-conv: wave gs handles groups {gs, gs+4}; x -> Xt transposed scalar
  {
    const int l = tid & 63, gs = tid >> 6;
    const int t = (c<<6) + l;
    #pragma unroll
    for (int i=0;i<2;i++){
      int g = gs + i*4;
      int ch0 = (h<<6)+g*8;
      u16x8 o;
      conv8(xraw, cwTs, cbs, seqbase, t, ch0, full, &o);
      #pragma unroll
      for (int j=0;j<8;j++) Xt[(g*8+j)*72 + l] = o[j];
    }
  }
  // B, C from xbc (vec8)
  {
    int l = tid>>2, part = tid&3;
    u16x8 vv = *(const u16x8*)&xbc[(size_t)(tokbase+l)*32 + part*8];
    if (part < 2) *(u16x8*)&Bp[l*24 + part*8] = vv;
    else          *(u16x8*)&Cp[l*24 + (part-2)*8] = vv;
  }
  __syncthreads();

  const int wid = tid>>6, lane = tid&63;
  const int la = lane&15, kq = lane>>4;
  const int L0 = wid*16;
  const f32x4 zero4 = {0.f,0.f,0.f,0.f};
  const bf16x8 zfrag = {0,0,0,0,0,0,0,0};

  // per-thread l-row exp factors (reused by Sb and Y_off)
  float el[4];
  #pragma unroll
  for (int r=0; r<4; r++) el[r] = exps_s[L0 + kq*4 + r];

  // CB = C·B^T (K=32, upper-half fragments zero) -> factored mask/scale -> Sb bf16
  {
    bf16x8 a = (kq<2) ? *(const bf16x8*)&Cp[(L0+la)*24 + kq*8] : zfrag;
    f32x4 cbacc[4];
    #pragma unroll
    for (int nf=0; nf<4; nf++){
      bf16x8 b = (kq<2) ? *(const bf16x8*)&Bp[(nf*16+la)*24 + kq*8] : zfrag;
      cbacc[nf] = __builtin_amdgcn_mfma_f32_16x16x32_bf16(a, b, zero4, 0,0,0);
    }
    #pragma unroll
    for (int nf=0; nf<4; nf++){
      int s = nf*16 + la;
      const float es = endt_s[s];
      float vv[4];
      #pragma unroll
      for (int r=0; r<4; r++){
        int l = L0 + kq*4 + r;
        float v = 0.f;
        if (s <= l) v = el[r]*es*cbacc[nf][r];
        if (s == l) v += Dh;
        vv[r] = v;
      }
      unsigned int p01 = cvtpk(vv[0], vv[1]);
      unsigned int p23 = cvtpk(vv[2], vv[3]);
      int lb = L0 + kq*4;
      Sb[(lb+0)*72 + s] = (unsigned short)p01;
      Sb[(lb+1)*72 + s] = (unsigned short)(p01>>16);
      Sb[(lb+2)*72 + s] = (unsigned short)p23;
      Sb[(lb+3)*72 + s] = (unsigned short)(p23>>16);
    }
  }
  // Y_off = C·states^T (states fragments from global), scale el[r]
  f32x4 ya[4];
  {
    bf16x8 a = (kq<2) ? *(const bf16x8*)&Cp[(L0+la)*24 + kq*8] : zfrag;
    #pragma unroll
    for (int nf=0; nf<4; nf++){
      bf16x8 b = (kq<2) ? *(const bf16x8*)&states[((size_t)bx<<10) + (size_t)(nf*16+la)*16 + kq*8] : zfrag;
      ya[nf] = __builtin_amdgcn_mfma_f32_16x16x32_bf16(a, b, zero4, 0,0,0);
    }
    #pragma unroll
    for (int nf=0; nf<4; nf++)
      #pragma unroll
      for (int r=0; r<4; r++) ya[nf][r] *= el[r];
  }
  // Y_diag += Sb·Xt^T (K=64); A-operand reads only own-wave Sb rows
  #pragma unroll
  for (int kt=0; kt<2; kt++){
    bf16x8 a = *(const bf16x8*)&Sb[(L0+la)*72 + kt*32+kq*8];
    #pragma unroll
    for (int nf=0; nf<4; nf++){
      bf16x8 b = *(const bf16x8*)&Xt[(nf*16+la)*72 + kt*32+kq*8];
      ya[nf] = __builtin_amdgcn_mfma_f32_16x16x32_bf16(a, b, ya[nf], 0,0,0);
    }
  }
  __syncthreads();   // all waves done reading Xt/Sb -> Yl alias safe
  #pragma unroll
  for (int nf=0; nf<4; nf++){
    #pragma unroll
    for (int r=0; r<4; r++){
      int l = L0 + kq*4 + r, p = nf*16 + la;
      Yl[l*68 + p] = ya[nf][r];
    }
  }
  __syncthreads();
  #pragma unroll
  for (int i=0;i<2;i++){
    int u = tid + (i<<8);
    int l = u>>3, g = u&7;
    size_t gidx = (size_t)(tokbase+l)*DIN + (h<<6) + g*8;
    u16x8 z8 = *(const u16x8*)&zyf[gidx];
    float yv[8];
    float ps = 0.f;
    #pragma unroll
    for (int j=0;j<8;j++){
      float y = Yl[l*68 + g*8 + j];
      float zv = bf2f(z8[j]);
      yv[j] = y * zv * sigm(zv);
      ps = fmaf(yv[j], yv[j], ps);
    }
    unsigned int pr[4];
    pr[0]=cvtpk(yv[0],yv[1]); pr[1]=cvtpk(yv[2],yv[3]);
    pr[2]=cvtpk(yv[4],yv[5]); pr[3]=cvtpk(yv[6],yv[7]);
    *(u16x8*)&zyf[gidx] = *(const u16x8*)pr;
    ps += __shfl_xor(ps, 1); ps += __shfl_xor(ps, 2); ps += __shfl_xor(ps, 4);
    if (g == 0) ssqp[(size_t)(tokbase+l)*NHEADS + h] = ps;
  }
}

// ---------------- predgate -------------------------------------------------------
__global__ __launch_bounds__(256) void predgate_kernel(
  const unsigned short* __restrict__ fused, const float* __restrict__ sample,
  const unsigned short* __restrict__ gwb, const float* __restrict__ gb,
  const float* __restrict__ ow, const float* __restrict__ ob,
  const float* __restrict__ rg, float* __restrict__ pred)
{
  __shared__ __align__(16) unsigned short Ws[64*72];
  __shared__ __align__(16) float Gp[128*68];
  const int tid = threadIdx.x;
  const int m0 = blockIdx.x<<7;
  const int wid = tid>>6, lane = tid&63;
  const int la = lane&15, kq = lane>>4;
  const int mw = m0 + wid*32;

  bf16x8 af[2][2];
  #pragma unroll
  for (int ki=0; ki<2; ki++){
    int k = ki*32 + kq*8;
    #pragma unroll
    for (int mf=0; mf<2; mf++){
      int row = mw + mf*16 + la;
      float4 s0 = *(const float4*)&sample[(size_t)row*64 + k];
      float4 s1 = *(const float4*)&sample[(size_t)row*64 + k + 4];
      unsigned int pr[4];
      pr[0]=cvtpk(s0.x,s0.y); pr[1]=cvtpk(s0.z,s0.w);
      pr[2]=cvtpk(s1.x,s1.y); pr[3]=cvtpk(s1.z,s1.w);
      af[ki][mf] = *(const bf16x8*)pr;
    }
  }
  const float ob0 = ob[0];
  const int prow = tid>>1, phalf = tid&1;
  float rs = 0.f;

  #pragma unroll
  for (int nt=0; nt<2; nt++){
    int n0 = nt<<6;
    #pragma unroll
    for (int i=0;i<2;i++){
      int slot = tid + (i<<8);
      int row = slot>>3, g = slot&7;
      *(u16x8*)&Ws[row*72 + g*8] = *(const u16x8*)&gwb[(size_t)(n0+row)*64 + g*8];
    }
    __syncthreads();
    f32x4 acc[2][4] = {};
    #pragma unroll
    for (int ki=0; ki<2; ki++){
      #pragma unroll
      for (int nf=0; nf<4; nf++){
        bf16x8 bfr = *(const bf16x8*)&Ws[(nf*16 + la)*72 + ki*32 + kq*8];
        #pragma unroll
        for (int mf=0; mf<2; mf++)
          acc[mf][nf] = __builtin_amdgcn_mfma_f32_16x16x32_bf16(af[ki][mf], bfr, acc[mf][nf], 0,0,0);
      }
    }
    #pragma unroll
    for (int mf=0; mf<2; mf++){
      #pragma unroll
      for (int nf=0; nf<4; nf++){
        #pragma unroll
        for (int r=0; r<4; r++){
          int row = wid*32 + mf*16 + kq*4 + r;
          int col = nf*16 + la;
          int n = n0 + col;
          Gp[row*68 + col] = sigm(acc[mf][nf][r] + gb[n]) * ow[n];
        }
      }
    }
    __syncthreads();
    #pragma unroll
    for (int q=0; q<4; q++){
      int col0 = phalf*32 + q*8;
      u16x8 f8 = *(const u16x8*)&fused[(size_t)(m0+prow)*128 + n0 + col0];
      float4 g0 = *(const float4*)&Gp[prow*68 + col0];
      float4 g1 = *(const float4*)&Gp[prow*68 + col0 + 4];
      rs = fmaf(bf2f(f8[0]), g0.x, rs); rs = fmaf(bf2f(f8[1]), g0.y, rs);
      rs = fmaf(bf2f(f8[2]), g0.z, rs); rs = fmaf(bf2f(f8[3]), g0.w, rs);
      rs = fmaf(bf2f(f8[4]), g1.x, rs); rs = fmaf(bf2f(f8[5]), g1.y, rs);
      rs = fmaf(bf2f(f8[6]), g1.z, rs); rs = fmaf(bf2f(f8[7]), g1.w, rs);
    }
    __syncthreads();
  }
  rs += __shfl_xor(rs, 1);
  if (phalf == 0){
    int m = m0 + prow;
    pred[m] = (rs + ob0) * sigm(rg[m & 4095]);
  }
}

extern "C" void kernel_launch(void* const* d_in, const int* in_sizes, int n_in,
                              void* d_out, int out_size, void* d_ws, size_t ws_size,
                              hipStream_t stream)
{
  const float* expr      = (const float*)d_in[0];
  const float* noise     = (const float*)d_in[1];
  const float* expr_w    = (const float*)d_in[2];
  const float* expr_b    = (const float*)d_in[3];
  const float* in_proj_w = (const float*)d_in[4];
  const float* conv_w    = (const float*)d_in[5];
  const float* conv_b    = (const float*)d_in[6];
  const float* dt_bias   = (const float*)d_in[7];
  const float* A_log     = (const float*)d_in[8];
  const float* D_par     = (const float*)d_in[9];
  const float* norm_w    = (const float*)d_in[10];
  const float* out_proj_w= (const float*)d_in[11];
  const float* fusion_w  = (const float*)d_in[12];
  const float* fusion_b  = (const float*)d_in[13];
  const float* lm_w      = (const float*)d_in[14];
  const float* lm_b      = (const float*)d_in[15];
  const float* lv_w      = (const float*)d_in[16];
  const float* lv_b      = (const float*)d_in[17];
  const float* gate_w    = (const float*)d_in[18];
  const float* gate_b    = (const float*)d_in[19];
  const float* outp_w    = (const float*)d_in[20];
  const float* outp_b    = (const float*)d_in[21];
  const float* reg_gate  = (const float*)d_in[22];

  const size_t WBYTES = 956416;
  const int IMAX = 0x7fffffff;
  int BG = 0;
  const int cands[5] = {16, 8, 4, 2, 1};
  for (int ci = 0; ci < 5; ci++) {
    int c2 = cands[ci];
    size_t MG2c = (size_t)2 * c2 * LSEQ;
    size_t need = WBYTES + MG2c*1584 + (size_t)c2*2048 + 256;
    if (need <= ws_size) { BG = c2; break; }
  }
  if (!BG) return;
  const size_t MG  = (size_t)BG * LSEQ;
  const size_t MG2 = 2*MG;

  unsigned short* wip = (unsigned short*)d_ws;
  unsigned short* wop = wip + 280576;
  unsigned short* wfu = wop + 131072;
  unsigned short* wlm = wfu + 32768;
  unsigned short* wlv = wlm + 8192;
  unsigned short* wgw = wlv + 8192;
  float* cwT   = (float*)(wgw + 8192);
  float* dtsp  = (float*)((char*)d_ws + WBYTES);
  float* acs   = dtsp + MG2*4;
  float* atot  = acs  + MG2*4;
  float* ssqp  = atot + (size_t)2*BG*256;
  unsigned short* statesb = (unsigned short*)(ssqp + MG2*4);
  unsigned short* xbc   = statesb + MG2*64;
  unsigned short* zyf   = xbc + MG2*32;
  unsigned short* xrawb = zyf + MG2*256;
  unsigned short* act   = xrawb + MG2*288;
  unsigned short* actA  = act;
  unsigned short* actB  = act + MG*128;
  unsigned short* fusedbf = zyf;

  float* out_pred_g = (float*)d_out;
  float* out_lm_g   = out_pred_g + (size_t)16*LSEQ;
  float* out_lv_g   = out_lm_g   + (size_t)16*LSEQ*LAT;
  float* out_samp_g = out_lv_g   + (size_t)16*LSEQ*LAT;

  cvt_kernel<<<(280576+255)/256, 256, 0, stream>>>(in_proj_w, wip, 280576);
  cvt_nw_kernel<<<131072/256,    256, 0, stream>>>(out_proj_w, norm_w, wop, 131072);
  cvt_kernel<<<32768/256,        256, 0, stream>>>(fusion_w, wfu, 32768);
  cvt_kernel<<<8192/256,         256, 0, stream>>>(lm_w, wlm, 8192);
  cvt_kernel<<<8192/256,         256, 0, stream>>>(lv_w, wlv, 8192);
  cvt_kernel<<<8192/256,         256, 0, stream>>>(gate_w, wgw, 8192);
  cvt_cw_kernel<<<(4608+255)/256, 256, 0, stream>>>(conv_w, cwT);

  for (int b0 = 0; b0 < 16; b0 += BG) {
    float* out_pred = out_pred_g + (size_t)b0*LSEQ;
    float* out_lm   = out_lm_g   + (size_t)b0*LSEQ*LAT;
    float* out_lv   = out_lv_g   + (size_t)b0*LSEQ*LAT;
    float* out_samp = out_samp_g + (size_t)b0*LSEQ*LAT;
    const float* nz = noise      + (size_t)b0*LSEQ*LAT;

    embed_kernel<<<(MG*128)/256, 256, 0, stream>>>(expr + (size_t)b0*LSEQ, expr_w, expr_b, actA, actB);

    for (int p = 0; p < 2; p++) {
      const unsigned short* Wi = wip + (size_t)p*DPROJ*HMOD;
      const unsigned short* Wo = wop + (size_t)p*HMOD*DIN;
      const float* cwTl = cwT + (size_t)p*1152;
      const float* cb   = conv_b + (size_t)p*CONVD;
      const float* dtb  = dt_bias + (size_t)p*NHEADS;
      const float* Al   = A_log + (size_t)p*NHEADS;
      const float* Dl   = D_par + (size_t)p*NHEADS;

      gemm3<128,3,1><<<dim3(MG2/128, 3), 256, 0, stream>>>(act, nullptr, Wi, dtb, nullptr, nullptr,
        zyf, xrawb, dtsp, nullptr, nullptr, nullptr, DPROJ, 0, (int)MG, 2*DPROJ*HMOD, 2*NHEADS);
      conv_bc_kernel<<<(MG2*4)/256, 256, 0, stream>>>(xrawb, cwTl, cb, xbc, (int)MG);
      ssd_front<<<2*BG*256, 256, 0, stream>>>(xrawb, xbc, dtsp, Al, cwTl, cb, statesb, acs, atot, BG);
      scan_kernel<<<(2*BG*LSEQ)/256, 256, 0, stream>>>(statesb, atot);
      ssd_back<<<2*BG*256, 256, 0, stream>>>(xrawb, xbc, zyf, dtsp, acs, statesb, Dl, cwTl, cb, ssqp, BG);
      gemm3<256,1,4><<<dim3(MG2/128, 2), 256, 0, stream>>>(zyf, nullptr, Wo, nullptr, nullptr, ssqp,
        act, nullptr, nullptr, nullptr, nullptr, nullptr, HMOD, HMOD, (int)MG, 2*HMOD*DIN, 0);
    }

    gemm3<256,1,2><<<dim3(MG/128, 2), 256, 0, stream>>>(actA, actB, wfu, fusion_b, nullptr, nullptr,
      fusedbf, nullptr, nullptr, nullptr, nullptr, nullptr, HMOD, HMOD, IMAX, 0, 0);
    gemm3<128,2,5><<<dim3(MG/128, 1), 256, 0, stream>>>(fusedbf, nullptr, wlm, lm_b, lv_b, nullptr,
      nullptr, nullptr, out_lm, out_lv, nz, out_samp, 128, LAT, IMAX, 0, 0);
    predgate_kernel<<<MG/128, 256, 0, stream>>>(fusedbf, out_samp, wgw, gate_b, outp_w, outp_b, reg_gate, out_pred);
  }
}